// Round 1
// baseline (715.692 us; speedup 1.0000x reference)
//
#include <hip/hip_runtime.h>
#include <math.h>

#define NEG_SLOPE 0.2f

// ---------------------------------------------------------------------------
// SGEMM: C[M,N] = A[M,K] @ B[K,N], all row-major fp32.
// 64x64 tile, 256 threads, 4x4 per thread, K-step 16.
// Requires N % 64 == 0 and K % 16 == 0 (true here: N in {256,64}, K in {256}).
// ---------------------------------------------------------------------------
__global__ __launch_bounds__(256) void sgemm64(const float* __restrict__ A,
                                               const float* __restrict__ B,
                                               float* __restrict__ C,
                                               int M, int N, int K)
{
    __shared__ float As[16][68];   // [k][m], padded
    __shared__ float Bs[16][68];   // [k][n], padded
    const int tid = threadIdx.x;
    const int m0 = blockIdx.y * 64;
    const int n0 = blockIdx.x * 64;
    const int tr = tid >> 4;        // 0..15 -> m group
    const int tc = tid & 15;        // 0..15 -> n group
    const int lrow = tid >> 2;      // 0..63 A-load row
    const int lc4  = tid & 3;       // 0..3  A-load k-group
    const int lkb  = tid >> 4;      // 0..15 B-load k row
    const int lnb  = (tid & 15) * 4;

    float acc[4][4];
#pragma unroll
    for (int i = 0; i < 4; ++i)
#pragma unroll
        for (int j = 0; j < 4; ++j) acc[i][j] = 0.f;

    for (int k0 = 0; k0 < K; k0 += 16) {
        float4 a4 = make_float4(0.f, 0.f, 0.f, 0.f);
        if (m0 + lrow < M)
            a4 = *(const float4*)&A[(size_t)(m0 + lrow) * K + k0 + lc4 * 4];
        As[lc4 * 4 + 0][lrow] = a4.x;
        As[lc4 * 4 + 1][lrow] = a4.y;
        As[lc4 * 4 + 2][lrow] = a4.z;
        As[lc4 * 4 + 3][lrow] = a4.w;
        float4 b4 = *(const float4*)&B[(size_t)(k0 + lkb) * N + n0 + lnb];
        *(float4*)&Bs[lkb][lnb] = b4;
        __syncthreads();
#pragma unroll
        for (int kk = 0; kk < 16; ++kk) {
            float4 av = *(const float4*)&As[kk][tr * 4];
            float4 bv = *(const float4*)&Bs[kk][tc * 4];
            float a[4] = {av.x, av.y, av.z, av.w};
            float b[4] = {bv.x, bv.y, bv.z, bv.w};
#pragma unroll
            for (int i = 0; i < 4; ++i)
#pragma unroll
                for (int j = 0; j < 4; ++j)
                    acc[i][j] = fmaf(a[i], b[j], acc[i][j]);
        }
        __syncthreads();
    }
#pragma unroll
    for (int i = 0; i < 4; ++i) {
        int mrow = m0 + tr * 4 + i;
        if (mrow < M) {
            float4 o = make_float4(acc[i][0], acc[i][1], acc[i][2], acc[i][3]);
            *(float4*)&C[(size_t)mrow * N + n0 + tc * 4] = o;
        }
    }
}

// ---------------------------------------------------------------------------
// CSR build: counts -> chunk sums -> serial chunk scan -> block scan + write
// ---------------------------------------------------------------------------
__global__ void k_count(const int* __restrict__ dst, int E, int* __restrict__ counts)
{
    int i = blockIdx.x * blockDim.x + threadIdx.x;
    if (i < E) atomicAdd(&counts[dst[i]], 1);
}

__global__ void k_chunksum(const int* __restrict__ counts, int N, int* __restrict__ chunk)
{
    __shared__ int sm[256];
    const int t = threadIdx.x;
    const int base = blockIdx.x * 1024;
    int s = 0;
    for (int i = t; i < 1024; i += 256) {
        int idx = base + i;
        s += (idx < N) ? counts[idx] : 0;
    }
    sm[t] = s;
    __syncthreads();
    for (int off = 128; off; off >>= 1) {
        if (t < off) sm[t] += sm[t + off];
        __syncthreads();
    }
    if (t == 0) chunk[blockIdx.x] = sm[0];
}

__global__ void k_scanchunk(int* __restrict__ chunk, int nchunks)
{
    if (blockIdx.x == 0 && threadIdx.x == 0) {
        int run = 0;
        for (int i = 0; i < nchunks; ++i) {
            int c = chunk[i];
            chunk[i] = run;
            run += c;
        }
        chunk[nchunks] = run;
    }
}

__global__ void k_scanwrite(const int* __restrict__ counts, int N,
                            const int* __restrict__ chunk,
                            int* __restrict__ offsets, int* __restrict__ cursor)
{
    __shared__ int sm[256];
    const int t = threadIdx.x;
    const int base = blockIdx.x * 1024 + t * 4;
    int v[4];
    int s = 0;
#pragma unroll
    for (int i = 0; i < 4; ++i) {
        v[i] = (base + i < N) ? counts[base + i] : 0;
        s += v[i];
    }
    sm[t] = s;
    __syncthreads();
    for (int off = 1; off < 256; off <<= 1) {
        int y = (t >= off) ? sm[t - off] : 0;
        __syncthreads();
        sm[t] += y;
        __syncthreads();
    }
    int run = chunk[blockIdx.x] + sm[t] - s;   // exclusive prefix for this thread
#pragma unroll
    for (int i = 0; i < 4; ++i) {
        if (base + i < N) {
            offsets[base + i] = run;
            cursor[base + i] = run;
        }
        run += v[i];
    }
    if (blockIdx.x == 0 && t == 0) offsets[N] = chunk[gridDim.x];
}

__global__ void k_fill(const int* __restrict__ src, const int* __restrict__ dst,
                       int E, int* __restrict__ cursor, int* __restrict__ csr_src)
{
    int i = blockIdx.x * blockDim.x + threadIdx.x;
    if (i < E) {
        int d = dst[i];
        int pos = atomicAdd(&cursor[d], 1);
        csr_src[pos] = src[i];
    }
}

// ---------------------------------------------------------------------------
// Layer-1 aggregation: one wave per node. H=8, C=32 -> 256 elems, 4/lane.
// Element i = lane + 64*j belongs to head (lane>>5) + 2*j.
// Online softmax over incoming edges; fused bias + ReLU epilogue.
// ---------------------------------------------------------------------------
__global__ __launch_bounds__(256) void agg1(const float* __restrict__ xl,
                                            const float* __restrict__ xr,
                                            const float* __restrict__ att,
                                            const float* __restrict__ bias,
                                            const int* __restrict__ offsets,
                                            const int* __restrict__ csr_src,
                                            float* __restrict__ h1, int N)
{
    const int wave = blockIdx.x * 4 + (threadIdx.x >> 6);
    const int lane = threadIdx.x & 63;
    if (wave >= N) return;
    const int n = wave;

    float attv[4], xrv[4];
#pragma unroll
    for (int j = 0; j < 4; ++j) {
        attv[j] = att[lane + 64 * j];
        xrv[j] = xr[(size_t)n * 256 + lane + 64 * j];
    }
    float m[4], l[4], acc[4];
#pragma unroll
    for (int j = 0; j < 4; ++j) { m[j] = -INFINITY; l[j] = 0.f; acc[j] = 0.f; }

    const int beg = offsets[n], end = offsets[n + 1];
    for (int k = beg; k < end; ++k) {
        const int s = csr_src[k];
        const float* xls = xl + (size_t)s * 256;
        float xlv[4], logit[4];
#pragma unroll
        for (int j = 0; j < 4; ++j) xlv[j] = xls[lane + 64 * j];
#pragma unroll
        for (int j = 0; j < 4; ++j) {
            float t = xlv[j] + xrv[j];
            t = (t > 0.f) ? t : NEG_SLOPE * t;
            float u = t * attv[j];
            // butterfly sum over the 32-lane half (this head's 32 channels)
            u += __shfl_xor(u, 1);
            u += __shfl_xor(u, 2);
            u += __shfl_xor(u, 4);
            u += __shfl_xor(u, 8);
            u += __shfl_xor(u, 16);
            logit[j] = u;
        }
#pragma unroll
        for (int j = 0; j < 4; ++j) {
            float nm = fmaxf(m[j], logit[j]);
            float sc = __expf(m[j] - nm);       // first edge: exp(-inf)=0
            float p = __expf(logit[j] - nm);
            acc[j] = acc[j] * sc + p * xlv[j];
            l[j] = l[j] * sc + p;
            m[j] = nm;
        }
    }
#pragma unroll
    for (int j = 0; j < 4; ++j) {
        float o = acc[j] / (l[j] + 1e-16f) + bias[lane + 64 * j];
        h1[(size_t)n * 256 + lane + 64 * j] = fmaxf(o, 0.f);   // ReLU between layers
    }
}

// ---------------------------------------------------------------------------
// Layer-2 aggregation: one wave per node. H=1, C=64 -> 1 elem/lane.
// Fused bias + log_softmax epilogue; writes both outputs.
// ---------------------------------------------------------------------------
__global__ __launch_bounds__(256) void agg2(const float* __restrict__ xl,
                                            const float* __restrict__ xr,
                                            const float* __restrict__ att,
                                            const float* __restrict__ bias,
                                            const int* __restrict__ offsets,
                                            const int* __restrict__ csr_src,
                                            float* __restrict__ out, int N)
{
    const int wave = blockIdx.x * 4 + (threadIdx.x >> 6);
    const int lane = threadIdx.x & 63;
    if (wave >= N) return;
    const int n = wave;

    const float attv = att[lane];
    const float xrv = xr[(size_t)n * 64 + lane];
    float m = -INFINITY, l = 0.f, acc = 0.f;

    const int beg = offsets[n], end = offsets[n + 1];
    for (int k = beg; k < end; ++k) {
        const int s = csr_src[k];
        const float xlv = xl[(size_t)s * 64 + lane];
        float t = xlv + xrv;
        t = (t > 0.f) ? t : NEG_SLOPE * t;
        float u = t * attv;
        u += __shfl_xor(u, 1);
        u += __shfl_xor(u, 2);
        u += __shfl_xor(u, 4);
        u += __shfl_xor(u, 8);
        u += __shfl_xor(u, 16);
        u += __shfl_xor(u, 32);     // full-wave sum: the single head's 64 channels
        float nm = fmaxf(m, u);
        float sc = __expf(m - nm);
        float p = __expf(u - nm);
        acc = acc * sc + p * xlv;
        l = l * sc + p;
        m = nm;
    }
    float h = acc / (l + 1e-16f) + bias[lane];
    out[(size_t)n * 64 + lane] = h;

    // log_softmax over the 64 channels (one per lane)
    float mx = h;
    mx = fmaxf(mx, __shfl_xor(mx, 1));
    mx = fmaxf(mx, __shfl_xor(mx, 2));
    mx = fmaxf(mx, __shfl_xor(mx, 4));
    mx = fmaxf(mx, __shfl_xor(mx, 8));
    mx = fmaxf(mx, __shfl_xor(mx, 16));
    mx = fmaxf(mx, __shfl_xor(mx, 32));
    float e = __expf(h - mx);
    float ssum = e;
    ssum += __shfl_xor(ssum, 1);
    ssum += __shfl_xor(ssum, 2);
    ssum += __shfl_xor(ssum, 4);
    ssum += __shfl_xor(ssum, 8);
    ssum += __shfl_xor(ssum, 16);
    ssum += __shfl_xor(ssum, 32);
    out[(size_t)(N + n) * 64 + lane] = h - mx - __logf(ssum);
}

// ---------------------------------------------------------------------------
extern "C" void kernel_launch(void* const* d_in, const int* in_sizes, int n_in,
                              void* d_out, int out_size, void* d_ws, size_t ws_size,
                              hipStream_t stream)
{
    const float* x    = (const float*)d_in[0];
    const int*   ei   = (const int*)d_in[1];
    const float* Wl1  = (const float*)d_in[2];
    const float* Wr1  = (const float*)d_in[3];
    const float* att1 = (const float*)d_in[4];
    const float* b1   = (const float*)d_in[5];
    const float* Wl2  = (const float*)d_in[6];
    const float* Wr2  = (const float*)d_in[7];
    const float* att2 = (const float*)d_in[8];
    const float* b2   = (const float*)d_in[9];
    float* out = (float*)d_out;

    const int F = 256;          // input features
    const int HC = 256;         // H*C (layer-1 width)
    const int OUT = 64;         // layer-2 width
    const int E = in_sizes[1] / 2;
    const int N = in_sizes[0] / F;

    const int* e_src = ei;
    const int* e_dst = ei + E;

    // ---- workspace layout (fp32 unless noted) ----
    float* xl1 = (float*)d_ws;                       // N*256
    float* xr1 = xl1 + (size_t)N * HC;               // N*256
    float* h1  = xr1 + (size_t)N * HC;               // N*256
    float* xl2 = xl1;                                // alias: xl1 dead after agg1
    float* xr2 = xr1;                                // alias
    int* offsets  = (int*)(h1 + (size_t)N * HC);     // N+1
    int* cursor   = offsets + (N + 1);               // N+1
    int* counts   = cursor + (N + 1);                // N
    int* chunkoff = counts + N;                      // <=64+1
    int* csr_src  = chunkoff + 66;                   // E

    const int nchunks = (N + 1023) / 1024;

    // ---- CSR build ----
    hipMemsetAsync(counts, 0, (size_t)N * sizeof(int), stream);
    k_count<<<(E + 255) / 256, 256, 0, stream>>>(e_dst, E, counts);
    k_chunksum<<<nchunks, 256, 0, stream>>>(counts, N, chunkoff);
    k_scanchunk<<<1, 64, 0, stream>>>(chunkoff, nchunks);
    k_scanwrite<<<nchunks, 256, 0, stream>>>(counts, N, chunkoff, offsets, cursor);
    k_fill<<<(E + 255) / 256, 256, 0, stream>>>(e_src, e_dst, E, cursor, csr_src);

    // ---- layer 1 ----
    dim3 g1(HC / 64, (N + 63) / 64);
    sgemm64<<<g1, 256, 0, stream>>>(x, Wl1, xl1, N, HC, F);
    sgemm64<<<g1, 256, 0, stream>>>(x, Wr1, xr1, N, HC, F);
    agg1<<<(N + 3) / 4, 256, 0, stream>>>(xl1, xr1, att1, b1, offsets, csr_src, h1, N);

    // ---- layer 2 ----
    dim3 g2(OUT / 64, (N + 63) / 64);
    sgemm64<<<g2, 256, 0, stream>>>(h1, Wl2, xl2, N, OUT, HC);
    sgemm64<<<g2, 256, 0, stream>>>(h1, Wr2, xr2, N, OUT, HC);
    agg2<<<(N + 3) / 4, 256, 0, stream>>>(xl2, xr2, att2, b2, offsets, csr_src, out, N);
}

// Round 2
// 568.944 us; speedup vs baseline: 1.2579x; 1.2579x over previous
//
#include <hip/hip_runtime.h>
#include <hip/hip_bf16.h>
#include <math.h>

#define NEG_SLOPE 0.2f

typedef __attribute__((ext_vector_type(8))) short short8;
typedef __attribute__((ext_vector_type(4))) float floatx4;

__device__ inline ushort f2b(float f) {
    __hip_bfloat16 b = __float2bfloat16(f);
    return *(ushort*)&b;
}
__device__ inline float b2f(ushort u) {
    union { unsigned int i; float f; } c;
    c.i = ((unsigned int)u) << 16;
    return c.f;
}

// ---------------------------------------------------------------------------
// bf16 MFMA GEMM: C[M,N] = A[M,K] @ Bt[N,K]^T, A/Bt/C bf16 row-major.
// 256 threads = 4 waves; each wave computes a 64x64 tile of C via 4x4 grid of
// 16x16x32 MFMAs. BK=32. Weights pre-transposed so both frags are k-contiguous.
// ---------------------------------------------------------------------------
template<int BM, int BN>
__global__ __launch_bounds__(256) void gemm_bf16(const ushort* __restrict__ A,
                                                 const ushort* __restrict__ Bt,
                                                 ushort* __restrict__ C,
                                                 int M, int N, int K)
{
    constexpr int SA = 40;                       // row stride in LDS (pad 8 bf16)
    __shared__ ushort As[BM * SA];
    __shared__ ushort Bs[BN * SA];
    const int tid = threadIdx.x;
    const int w = tid >> 6, lane = tid & 63;
    const int mw = (BM == 128) ? (w & 1) * 64 : w * 64;
    const int nw = (BM == 128) ? (w >> 1) * 64 : 0;
    const int m0 = blockIdx.y * BM;
    const int n0 = blockIdx.x * BN;
    const int lm = lane & 15;                    // row/col within 16-tile
    const int kg = lane >> 4;                    // k-group 0..3 (k = kg*8+j)

    floatx4 acc[4][4];
#pragma unroll
    for (int i = 0; i < 4; ++i)
#pragma unroll
        for (int j = 0; j < 4; ++j) acc[i][j] = (floatx4)0.f;

    for (int k0 = 0; k0 < K; k0 += 32) {
        // stage A tile: BM rows x 32 k, ushort8 per thread per iter
#pragma unroll
        for (int it = 0; it < BM / 64; ++it) {
            int idx = it * 256 + tid;
            int row = idx >> 2, kc = idx & 3;
            int grow = m0 + row;
            if (grow >= M) grow = M - 1;         // clamp (stores masked later)
            short8 v = *(const short8*)&A[(size_t)grow * K + k0 + kc * 8];
            *(short8*)&As[row * SA + kc * 8] = v;
        }
        // stage B tile: BN rows x 32 k
#pragma unroll
        for (int it = 0; it < BN / 64; ++it) {
            int idx = it * 256 + tid;
            int row = idx >> 2, kc = idx & 3;
            short8 v = *(const short8*)&Bt[(size_t)(n0 + row) * K + k0 + kc * 8];
            *(short8*)&Bs[row * SA + kc * 8] = v;
        }
        __syncthreads();
        short8 a[4], b[4];
#pragma unroll
        for (int i = 0; i < 4; ++i)
            a[i] = *(const short8*)&As[(mw + i * 16 + lm) * SA + kg * 8];
#pragma unroll
        for (int j = 0; j < 4; ++j)
            b[j] = *(const short8*)&Bs[(nw + j * 16 + lm) * SA + kg * 8];
#pragma unroll
        for (int i = 0; i < 4; ++i)
#pragma unroll
            for (int j = 0; j < 4; ++j)
                acc[i][j] = __builtin_amdgcn_mfma_f32_16x16x32_bf16(a[i], b[j], acc[i][j], 0, 0, 0);
        __syncthreads();
    }

    // epilogue: C/D layout col = lane&15, row = (lane>>4)*4 + reg  [m89]
#pragma unroll
    for (int i = 0; i < 4; ++i) {
        int rbase = m0 + mw + i * 16 + (lane >> 4) * 4;
#pragma unroll
        for (int j = 0; j < 4; ++j) {
            int col = n0 + nw + j * 16 + lm;
#pragma unroll
            for (int r = 0; r < 4; ++r) {
                int row = rbase + r;
                if (row < M) C[(size_t)row * N + col] = f2b(acc[i][j][r]);
            }
        }
    }
}

// ---------------------------------------------------------------------------
// dtype prep
// ---------------------------------------------------------------------------
__global__ void k_cast_bf16(const float* __restrict__ in, ushort* __restrict__ out, int n)
{
    int idx = (blockIdx.x * blockDim.x + threadIdx.x) * 4;
    if (idx < n) {
        float4 v = *(const float4*)&in[idx];
        ushort4 o;
        o.x = f2b(v.x); o.y = f2b(v.y); o.z = f2b(v.z); o.w = f2b(v.w);
        *(ushort4*)&out[idx] = o;
    }
}

// W[K,N] fp32 -> Wt[N,K] bf16 (tiny matrices; naive is fine)
__global__ void k_tcast(const float* __restrict__ W, ushort* __restrict__ Wt, int K, int N)
{
    int i = blockIdx.x * blockDim.x + threadIdx.x;
    if (i < K * N) {
        int k = i / N, n = i % N;
        Wt[(size_t)n * K + k] = f2b(W[i]);
    }
}

// ---------------------------------------------------------------------------
// CSR build: counts -> chunk sums -> serial chunk scan -> block scan + write
// ---------------------------------------------------------------------------
__global__ void k_count(const int* __restrict__ dst, int E, int* __restrict__ counts)
{
    int i = blockIdx.x * blockDim.x + threadIdx.x;
    if (i < E) atomicAdd(&counts[dst[i]], 1);
}

__global__ void k_chunksum(const int* __restrict__ counts, int N, int* __restrict__ chunk)
{
    __shared__ int sm[256];
    const int t = threadIdx.x;
    const int base = blockIdx.x * 1024;
    int s = 0;
    for (int i = t; i < 1024; i += 256) {
        int idx = base + i;
        s += (idx < N) ? counts[idx] : 0;
    }
    sm[t] = s;
    __syncthreads();
    for (int off = 128; off; off >>= 1) {
        if (t < off) sm[t] += sm[t + off];
        __syncthreads();
    }
    if (t == 0) chunk[blockIdx.x] = sm[0];
}

__global__ void k_scanchunk(int* __restrict__ chunk, int nchunks)
{
    if (blockIdx.x == 0 && threadIdx.x == 0) {
        int run = 0;
        for (int i = 0; i < nchunks; ++i) {
            int c = chunk[i];
            chunk[i] = run;
            run += c;
        }
        chunk[nchunks] = run;
    }
}

__global__ void k_scanwrite(const int* __restrict__ counts, int N,
                            const int* __restrict__ chunk,
                            int* __restrict__ offsets, int* __restrict__ cursor)
{
    __shared__ int sm[256];
    const int t = threadIdx.x;
    const int base = blockIdx.x * 1024 + t * 4;
    int v[4];
    int s = 0;
#pragma unroll
    for (int i = 0; i < 4; ++i) {
        v[i] = (base + i < N) ? counts[base + i] : 0;
        s += v[i];
    }
    sm[t] = s;
    __syncthreads();
    for (int off = 1; off < 256; off <<= 1) {
        int y = (t >= off) ? sm[t - off] : 0;
        __syncthreads();
        sm[t] += y;
        __syncthreads();
    }
    int run = chunk[blockIdx.x] + sm[t] - s;
#pragma unroll
    for (int i = 0; i < 4; ++i) {
        if (base + i < N) {
            offsets[base + i] = run;
            cursor[base + i] = run;
        }
        run += v[i];
    }
    if (blockIdx.x == 0 && t == 0) offsets[N] = chunk[gridDim.x];
}

__global__ void k_fill(const int* __restrict__ src, const int* __restrict__ dst,
                       int E, int* __restrict__ cursor, int* __restrict__ csr_src)
{
    int i = blockIdx.x * blockDim.x + threadIdx.x;
    if (i < E) {
        int d = dst[i];
        int pos = atomicAdd(&cursor[d], 1);
        csr_src[pos] = src[i];
    }
}

// ---------------------------------------------------------------------------
// Layer-1 aggregation: one wave per node. H=8, C=32 -> 256 elems, 4/lane.
// xl/xr bf16; online softmax; fused bias + ReLU; writes h1 as bf16.
// ---------------------------------------------------------------------------
__global__ __launch_bounds__(256) void agg1(const ushort* __restrict__ xl,
                                            const ushort* __restrict__ xr,
                                            const float* __restrict__ att,
                                            const float* __restrict__ bias,
                                            const int* __restrict__ offsets,
                                            const int* __restrict__ csr_src,
                                            ushort* __restrict__ h1, int N)
{
    const int wave = blockIdx.x * 4 + (threadIdx.x >> 6);
    const int lane = threadIdx.x & 63;
    if (wave >= N) return;
    const int n = wave;

    float attv[4], xrv[4];
#pragma unroll
    for (int j = 0; j < 4; ++j) {
        attv[j] = att[lane + 64 * j];
        xrv[j] = b2f(xr[(size_t)n * 256 + lane + 64 * j]);
    }
    float m[4], l[4], acc[4];
#pragma unroll
    for (int j = 0; j < 4; ++j) { m[j] = -INFINITY; l[j] = 0.f; acc[j] = 0.f; }

    const int beg = offsets[n], end = offsets[n + 1];
    for (int k = beg; k < end; ++k) {
        const int s = csr_src[k];
        const ushort* xls = xl + (size_t)s * 256;
        float xlv[4], logit[4];
#pragma unroll
        for (int j = 0; j < 4; ++j) xlv[j] = b2f(xls[lane + 64 * j]);
#pragma unroll
        for (int j = 0; j < 4; ++j) {
            float t = xlv[j] + xrv[j];
            t = (t > 0.f) ? t : NEG_SLOPE * t;
            float u = t * attv[j];
            u += __shfl_xor(u, 1);
            u += __shfl_xor(u, 2);
            u += __shfl_xor(u, 4);
            u += __shfl_xor(u, 8);
            u += __shfl_xor(u, 16);
            logit[j] = u;
        }
#pragma unroll
        for (int j = 0; j < 4; ++j) {
            float nm = fmaxf(m[j], logit[j]);
            float sc = __expf(m[j] - nm);
            float p = __expf(logit[j] - nm);
            acc[j] = acc[j] * sc + p * xlv[j];
            l[j] = l[j] * sc + p;
            m[j] = nm;
        }
    }
#pragma unroll
    for (int j = 0; j < 4; ++j) {
        float o = acc[j] / (l[j] + 1e-16f) + bias[lane + 64 * j];
        h1[(size_t)n * 256 + lane + 64 * j] = f2b(fmaxf(o, 0.f));
    }
}

// ---------------------------------------------------------------------------
// Layer-2 aggregation: one wave per node. H=1, C=64 -> 1 elem/lane.
// xl/xr bf16; fused bias + log_softmax; writes both fp32 outputs.
// ---------------------------------------------------------------------------
__global__ __launch_bounds__(256) void agg2(const ushort* __restrict__ xl,
                                            const ushort* __restrict__ xr,
                                            const float* __restrict__ att,
                                            const float* __restrict__ bias,
                                            const int* __restrict__ offsets,
                                            const int* __restrict__ csr_src,
                                            float* __restrict__ out, int N)
{
    const int wave = blockIdx.x * 4 + (threadIdx.x >> 6);
    const int lane = threadIdx.x & 63;
    if (wave >= N) return;
    const int n = wave;

    const float attv = att[lane];
    const float xrv = b2f(xr[(size_t)n * 64 + lane]);
    float m = -INFINITY, l = 0.f, acc = 0.f;

    const int beg = offsets[n], end = offsets[n + 1];
    for (int k = beg; k < end; ++k) {
        const int s = csr_src[k];
        const float xlv = b2f(xl[(size_t)s * 64 + lane]);
        float t = xlv + xrv;
        t = (t > 0.f) ? t : NEG_SLOPE * t;
        float u = t * attv;
        u += __shfl_xor(u, 1);
        u += __shfl_xor(u, 2);
        u += __shfl_xor(u, 4);
        u += __shfl_xor(u, 8);
        u += __shfl_xor(u, 16);
        u += __shfl_xor(u, 32);
        float nm = fmaxf(m, u);
        float sc = __expf(m - nm);
        float p = __expf(u - nm);
        acc = acc * sc + p * xlv;
        l = l * sc + p;
        m = nm;
    }
    float h = acc / (l + 1e-16f) + bias[lane];
    out[(size_t)n * 64 + lane] = h;

    float mx = h;
    mx = fmaxf(mx, __shfl_xor(mx, 1));
    mx = fmaxf(mx, __shfl_xor(mx, 2));
    mx = fmaxf(mx, __shfl_xor(mx, 4));
    mx = fmaxf(mx, __shfl_xor(mx, 8));
    mx = fmaxf(mx, __shfl_xor(mx, 16));
    mx = fmaxf(mx, __shfl_xor(mx, 32));
    float e = __expf(h - mx);
    float ssum = e;
    ssum += __shfl_xor(ssum, 1);
    ssum += __shfl_xor(ssum, 2);
    ssum += __shfl_xor(ssum, 4);
    ssum += __shfl_xor(ssum, 8);
    ssum += __shfl_xor(ssum, 16);
    ssum += __shfl_xor(ssum, 32);
    out[(size_t)(N + n) * 64 + lane] = h - mx - __logf(ssum);
}

// ---------------------------------------------------------------------------
extern "C" void kernel_launch(void* const* d_in, const int* in_sizes, int n_in,
                              void* d_out, int out_size, void* d_ws, size_t ws_size,
                              hipStream_t stream)
{
    const float* x    = (const float*)d_in[0];
    const int*   ei   = (const int*)d_in[1];
    const float* Wl1  = (const float*)d_in[2];
    const float* Wr1  = (const float*)d_in[3];
    const float* att1 = (const float*)d_in[4];
    const float* b1   = (const float*)d_in[5];
    const float* Wl2  = (const float*)d_in[6];
    const float* Wr2  = (const float*)d_in[7];
    const float* att2 = (const float*)d_in[8];
    const float* b2   = (const float*)d_in[9];
    float* out = (float*)d_out;

    const int F = 256, HC = 256, OUT = 64;
    const int E = in_sizes[1] / 2;
    const int N = in_sizes[0] / F;

    const int* e_src = ei;
    const int* e_dst = ei + E;

    // ---- workspace layout ----
    ushort* xb   = (ushort*)d_ws;                    // N*256
    ushort* wl1t = xb + (size_t)N * 256;             // 256x256 (Wt[N][K])
    ushort* wr1t = wl1t + 256 * 256;
    ushort* wl2t = wr1t + 256 * 256;                 // 64x256
    ushort* wr2t = wl2t + 64 * 256;
    ushort* xl1b = wr2t + 64 * 256;                  // N*256
    ushort* xr1b = xl1b + (size_t)N * 256;           // N*256
    ushort* h1b  = xr1b + (size_t)N * 256;           // N*256
    ushort* xl2b = h1b + (size_t)N * 256;            // N*64
    ushort* xr2b = xl2b + (size_t)N * 64;            // N*64
    int* offsets  = (int*)(xr2b + (size_t)N * 64);   // N+1
    int* cursor   = offsets + (N + 1);               // N+1
    int* counts   = cursor + (N + 1);                // N
    int* chunkoff = counts + N;                      // <=64+1
    int* csr_src  = chunkoff + 66;                   // E

    const int nchunks = (N + 1023) / 1024;

    // ---- dtype prep ----
    int tot = N * 256;
    k_cast_bf16<<<(tot / 4 + 255) / 256, 256, 0, stream>>>(x, xb, tot);
    k_tcast<<<(256 * 256 + 255) / 256, 256, 0, stream>>>(Wl1, wl1t, 256, 256);
    k_tcast<<<(256 * 256 + 255) / 256, 256, 0, stream>>>(Wr1, wr1t, 256, 256);
    k_tcast<<<(256 * 64 + 255) / 256, 256, 0, stream>>>(Wl2, wl2t, 256, 64);
    k_tcast<<<(256 * 64 + 255) / 256, 256, 0, stream>>>(Wr2, wr2t, 256, 64);

    // ---- CSR build ----
    hipMemsetAsync(counts, 0, (size_t)N * sizeof(int), stream);
    k_count<<<(E + 255) / 256, 256, 0, stream>>>(e_dst, E, counts);
    k_chunksum<<<nchunks, 256, 0, stream>>>(counts, N, chunkoff);
    k_scanchunk<<<1, 64, 0, stream>>>(chunkoff, nchunks);
    k_scanwrite<<<nchunks, 256, 0, stream>>>(counts, N, chunkoff, offsets, cursor);
    k_fill<<<(E + 255) / 256, 256, 0, stream>>>(e_src, e_dst, E, cursor, csr_src);

    // ---- layer 1 ----
    gemm_bf16<128, 128><<<dim3(HC / 128, (N + 127) / 128), 256, 0, stream>>>(xb, wl1t, xl1b, N, HC, F);
    gemm_bf16<128, 128><<<dim3(HC / 128, (N + 127) / 128), 256, 0, stream>>>(xb, wr1t, xr1b, N, HC, F);
    agg1<<<(N + 3) / 4, 256, 0, stream>>>(xl1b, xr1b, att1, b1, offsets, csr_src, h1b, N);

    // ---- layer 2 ----
    gemm_bf16<256, 64><<<dim3(OUT / 64, (N + 255) / 256), 256, 0, stream>>>(h1b, wl2t, xl2b, N, OUT, HC);
    gemm_bf16<256, 64><<<dim3(OUT / 64, (N + 255) / 256), 256, 0, stream>>>(h1b, wr2t, xr2b, N, OUT, HC);
    agg2<<<(N + 3) / 4, 256, 0, stream>>>(xl2b, xr2b, att2, b2, offsets, csr_src, out, N);
}

// Round 3
// 418.608 us; speedup vs baseline: 1.7097x; 1.3591x over previous
//
#include <hip/hip_runtime.h>
#include <hip/hip_bf16.h>
#include <math.h>

#define NEG_SLOPE 0.2f

typedef __attribute__((ext_vector_type(8))) short short8;
typedef __attribute__((ext_vector_type(4))) float floatx4;

__device__ inline ushort f2b(float f) {
    __hip_bfloat16 b = __float2bfloat16(f);
    return *(ushort*)&b;
}
__device__ inline float b2f(ushort u) {
    union { unsigned int i; float f; } c;
    c.i = ((unsigned int)u) << 16;
    return c.f;
}

// ---------------------------------------------------------------------------
// bf16 MFMA GEMM: C[M,N] = A[M,K] @ Bt[N,K]^T, A/Bt/C bf16 row-major.
// 256 threads = 4 waves; each wave computes a 64x64 tile of C via 4x4 grid of
// 16x16x32 MFMAs. BK=32. Weights pre-transposed so both frags are k-contiguous.
// ---------------------------------------------------------------------------
template<int BM, int BN>
__global__ __launch_bounds__(256) void gemm_bf16(const ushort* __restrict__ A,
                                                 const ushort* __restrict__ Bt,
                                                 ushort* __restrict__ C,
                                                 int M, int N, int K)
{
    constexpr int SA = 40;                       // row stride in LDS (pad 8 bf16)
    __shared__ ushort As[BM * SA];
    __shared__ ushort Bs[BN * SA];
    const int tid = threadIdx.x;
    const int w = tid >> 6, lane = tid & 63;
    const int mw = (BM == 128) ? (w & 1) * 64 : w * 64;
    const int nw = (BM == 128) ? (w >> 1) * 64 : 0;
    const int m0 = blockIdx.y * BM;
    const int n0 = blockIdx.x * BN;
    const int lm = lane & 15;
    const int kg = lane >> 4;

    floatx4 acc[4][4];
#pragma unroll
    for (int i = 0; i < 4; ++i)
#pragma unroll
        for (int j = 0; j < 4; ++j) acc[i][j] = (floatx4)0.f;

    for (int k0 = 0; k0 < K; k0 += 32) {
#pragma unroll
        for (int it = 0; it < BM / 64; ++it) {
            int idx = it * 256 + tid;
            int row = idx >> 2, kc = idx & 3;
            int grow = m0 + row;
            if (grow >= M) grow = M - 1;
            short8 v = *(const short8*)&A[(size_t)grow * K + k0 + kc * 8];
            *(short8*)&As[row * SA + kc * 8] = v;
        }
#pragma unroll
        for (int it = 0; it < BN / 64; ++it) {
            int idx = it * 256 + tid;
            int row = idx >> 2, kc = idx & 3;
            short8 v = *(const short8*)&Bt[(size_t)(n0 + row) * K + k0 + kc * 8];
            *(short8*)&Bs[row * SA + kc * 8] = v;
        }
        __syncthreads();
        short8 a[4], b[4];
#pragma unroll
        for (int i = 0; i < 4; ++i)
            a[i] = *(const short8*)&As[(mw + i * 16 + lm) * SA + kg * 8];
#pragma unroll
        for (int j = 0; j < 4; ++j)
            b[j] = *(const short8*)&Bs[(nw + j * 16 + lm) * SA + kg * 8];
#pragma unroll
        for (int i = 0; i < 4; ++i)
#pragma unroll
            for (int j = 0; j < 4; ++j)
                acc[i][j] = __builtin_amdgcn_mfma_f32_16x16x32_bf16(a[i], b[j], acc[i][j], 0, 0, 0);
        __syncthreads();
    }

#pragma unroll
    for (int i = 0; i < 4; ++i) {
        int rbase = m0 + mw + i * 16 + (lane >> 4) * 4;
#pragma unroll
        for (int j = 0; j < 4; ++j) {
            int col = n0 + nw + j * 16 + lm;
#pragma unroll
            for (int r = 0; r < 4; ++r) {
                int row = rbase + r;
                if (row < M) C[(size_t)row * N + col] = f2b(acc[i][j][r]);
            }
        }
    }
}

// ---------------------------------------------------------------------------
// dtype prep
// ---------------------------------------------------------------------------
__global__ void k_cast_bf16(const float* __restrict__ in, ushort* __restrict__ out, int n)
{
    int idx = (blockIdx.x * blockDim.x + threadIdx.x) * 4;
    if (idx < n) {
        float4 v = *(const float4*)&in[idx];
        ushort4 o;
        o.x = f2b(v.x); o.y = f2b(v.y); o.z = f2b(v.z); o.w = f2b(v.w);
        *(ushort4*)&out[idx] = o;
    }
}

__global__ void k_tcast(const float* __restrict__ W, ushort* __restrict__ Wt, int K, int N)
{
    int i = blockIdx.x * blockDim.x + threadIdx.x;
    if (i < K * N) {
        int k = i / N, n = i % N;
        Wt[(size_t)n * K + k] = f2b(W[i]);
    }
}

// ---------------------------------------------------------------------------
// CSR build
// ---------------------------------------------------------------------------
__global__ void k_count(const int* __restrict__ dst, int E, int* __restrict__ counts)
{
    int i = blockIdx.x * blockDim.x + threadIdx.x;
    if (i < E) atomicAdd(&counts[dst[i]], 1);
}

__global__ void k_chunksum(const int* __restrict__ counts, int N, int* __restrict__ chunk)
{
    __shared__ int sm[256];
    const int t = threadIdx.x;
    const int base = blockIdx.x * 1024;
    int s = 0;
    for (int i = t; i < 1024; i += 256) {
        int idx = base + i;
        s += (idx < N) ? counts[idx] : 0;
    }
    sm[t] = s;
    __syncthreads();
    for (int off = 128; off; off >>= 1) {
        if (t < off) sm[t] += sm[t + off];
        __syncthreads();
    }
    if (t == 0) chunk[blockIdx.x] = sm[0];
}

__global__ void k_scanchunk(int* __restrict__ chunk, int nchunks)
{
    if (blockIdx.x == 0 && threadIdx.x == 0) {
        int run = 0;
        for (int i = 0; i < nchunks; ++i) {
            int c = chunk[i];
            chunk[i] = run;
            run += c;
        }
        chunk[nchunks] = run;
    }
}

__global__ void k_scanwrite(const int* __restrict__ counts, int N,
                            const int* __restrict__ chunk,
                            int* __restrict__ offsets, int* __restrict__ cursor)
{
    __shared__ int sm[256];
    const int t = threadIdx.x;
    const int base = blockIdx.x * 1024 + t * 4;
    int v[4];
    int s = 0;
#pragma unroll
    for (int i = 0; i < 4; ++i) {
        v[i] = (base + i < N) ? counts[base + i] : 0;
        s += v[i];
    }
    sm[t] = s;
    __syncthreads();
    for (int off = 1; off < 256; off <<= 1) {
        int y = (t >= off) ? sm[t - off] : 0;
        __syncthreads();
        sm[t] += y;
        __syncthreads();
    }
    int run = chunk[blockIdx.x] + sm[t] - s;
#pragma unroll
    for (int i = 0; i < 4; ++i) {
        if (base + i < N) {
            offsets[base + i] = run;
            cursor[base + i] = run;
        }
        run += v[i];
    }
    if (blockIdx.x == 0 && t == 0) offsets[N] = chunk[gridDim.x];
}

__global__ void k_fill(const int* __restrict__ src, const int* __restrict__ dst,
                       int E, int* __restrict__ cursor, int* __restrict__ csr_src)
{
    int i = blockIdx.x * blockDim.x + threadIdx.x;
    if (i < E) {
        int d = dst[i];
        int pos = atomicAdd(&cursor[d], 1);
        csr_src[pos] = src[i];
    }
}

// ---------------------------------------------------------------------------
// Layer-1 aggregation: one wave per node. Lane owns 4 consecutive channels of
// ONE head: elem = (lane>>3)*32 + (lane&7)*4 + j; head = lane>>3.
// Per edge: 1 ushort4 gather, 4 local FMAs, 3-shuffle reduce over 8 lanes,
// single online-softmax state per lane. 1-deep pipeline on the gather chain.
// ---------------------------------------------------------------------------
__global__ __launch_bounds__(256) void agg1(const ushort* __restrict__ xl,
                                            const ushort* __restrict__ xr,
                                            const float* __restrict__ att,
                                            const float* __restrict__ bias,
                                            const int* __restrict__ offsets,
                                            const int* __restrict__ csr_src,
                                            ushort* __restrict__ h1, int N)
{
    const int wave = blockIdx.x * 4 + (threadIdx.x >> 6);
    const int lane = threadIdx.x & 63;
    if (wave >= N) return;
    const int n = wave;
    const int elem = (lane >> 3) * 32 + (lane & 7) * 4;

    const float4 attv = *(const float4*)&att[elem];
    ushort4 xr4 = *(const ushort4*)&xr[(size_t)n * 256 + elem];
    float xrv[4] = {b2f(xr4.x), b2f(xr4.y), b2f(xr4.z), b2f(xr4.w)};

    float m = -1e30f, l = 0.f;
    float acc[4] = {0.f, 0.f, 0.f, 0.f};

    const int beg = offsets[n], end = offsets[n + 1];
    if (beg < end) {
        int s = csr_src[beg];
        ushort4 xv = *(const ushort4*)&xl[(size_t)s * 256 + elem];
        for (int k = beg; k < end; ++k) {
            ushort4 cur = xv;
            if (k + 1 < end) {                 // prefetch next edge's row
                int s2 = csr_src[k + 1];
                xv = *(const ushort4*)&xl[(size_t)s2 * 256 + elem];
            }
            float xlv[4] = {b2f(cur.x), b2f(cur.y), b2f(cur.z), b2f(cur.w)};
            float u = 0.f;
#pragma unroll
            for (int j = 0; j < 4; ++j) {
                float t = xlv[j] + xrv[j];
                t = (t > 0.f) ? t : NEG_SLOPE * t;
                u = fmaf(t, ((const float*)&attv)[j], u);
            }
            u += __shfl_xor(u, 1);             // reduce over this head's 8 lanes
            u += __shfl_xor(u, 2);
            u += __shfl_xor(u, 4);
            float nm = fmaxf(m, u);
            float sc = __expf(m - nm);
            float p = __expf(u - nm);
#pragma unroll
            for (int j = 0; j < 4; ++j) acc[j] = acc[j] * sc + p * xlv[j];
            l = l * sc + p;
            m = nm;
        }
    }
    float rl = 1.f / (l + 1e-16f);
    const float4 bv = *(const float4*)&bias[elem];
    ushort4 o;
    o.x = f2b(fmaxf(acc[0] * rl + bv.x, 0.f));
    o.y = f2b(fmaxf(acc[1] * rl + bv.y, 0.f));
    o.z = f2b(fmaxf(acc[2] * rl + bv.z, 0.f));
    o.w = f2b(fmaxf(acc[3] * rl + bv.w, 0.f));
    *(ushort4*)&h1[(size_t)n * 256 + elem] = o;
}

// ---------------------------------------------------------------------------
// Layer-2 aggregation: one wave per node; 4 edge-slots in parallel (g=lane>>4),
// each 16-lane group owns the 64 channels (4/lane). 4-shuffle logit reduce,
// online softmax per group, associative merge across groups at the end.
// Fused bias + log_softmax epilogue; group 0 writes both outputs.
// ---------------------------------------------------------------------------
__global__ __launch_bounds__(256) void agg2(const ushort* __restrict__ xl,
                                            const ushort* __restrict__ xr,
                                            const float* __restrict__ att,
                                            const float* __restrict__ bias,
                                            const int* __restrict__ offsets,
                                            const int* __restrict__ csr_src,
                                            float* __restrict__ out, int N)
{
    const int wave = blockIdx.x * 4 + (threadIdx.x >> 6);
    const int lane = threadIdx.x & 63;
    if (wave >= N) return;
    const int n = wave;
    const int g = lane >> 4;         // edge sub-slot
    const int c0 = (lane & 15) * 4;  // channel quad

    const float4 attv = *(const float4*)&att[c0];
    ushort4 xr4 = *(const ushort4*)&xr[(size_t)n * 64 + c0];
    float xrv[4] = {b2f(xr4.x), b2f(xr4.y), b2f(xr4.z), b2f(xr4.w)};

    float m = -1e30f, l = 0.f;
    float acc[4] = {0.f, 0.f, 0.f, 0.f};

    const int beg = offsets[n], end = offsets[n + 1];
    for (int kb = beg; kb < end; kb += 4) {
        int k = kb + g;
        if (k < end) {
            int s = csr_src[k];
            ushort4 xv = *(const ushort4*)&xl[(size_t)s * 64 + c0];
            float xlv[4] = {b2f(xv.x), b2f(xv.y), b2f(xv.z), b2f(xv.w)};
            float u = 0.f;
#pragma unroll
            for (int j = 0; j < 4; ++j) {
                float t = xlv[j] + xrv[j];
                t = (t > 0.f) ? t : NEG_SLOPE * t;
                u = fmaf(t, ((const float*)&attv)[j], u);
            }
            u += __shfl_xor(u, 1);   // reduce over the 16-lane group
            u += __shfl_xor(u, 2);
            u += __shfl_xor(u, 4);
            u += __shfl_xor(u, 8);
            float nm = fmaxf(m, u);
            float sc = __expf(m - nm);
            float p = __expf(u - nm);
#pragma unroll
            for (int j = 0; j < 4; ++j) acc[j] = acc[j] * sc + p * xlv[j];
            l = l * sc + p;
            m = nm;
        }
    }
    // merge the 4 groups' online states (finite sentinel keeps this NaN-free)
#pragma unroll
    for (int off = 16; off <= 32; off <<= 1) {
        float mo = __shfl_xor(m, off);
        float lo = __shfl_xor(l, off);
        float ao[4];
#pragma unroll
        for (int j = 0; j < 4; ++j) ao[j] = __shfl_xor(acc[j], off);
        float nm = fmaxf(m, mo);
        float sa = __expf(m - nm);
        float sb = __expf(mo - nm);
#pragma unroll
        for (int j = 0; j < 4; ++j) acc[j] = acc[j] * sa + ao[j] * sb;
        l = l * sa + lo * sb;
        m = nm;
    }
    float rl = 1.f / (l + 1e-16f);
    const float4 bv = *(const float4*)&bias[c0];
    float h[4];
#pragma unroll
    for (int j = 0; j < 4; ++j) h[j] = acc[j] * rl + ((const float*)&bv)[j];

    // log_softmax over 64 channels (4/lane x 16 lanes)
    float mx = fmaxf(fmaxf(h[0], h[1]), fmaxf(h[2], h[3]));
    mx = fmaxf(mx, __shfl_xor(mx, 1));
    mx = fmaxf(mx, __shfl_xor(mx, 2));
    mx = fmaxf(mx, __shfl_xor(mx, 4));
    mx = fmaxf(mx, __shfl_xor(mx, 8));
    float ssum = __expf(h[0] - mx) + __expf(h[1] - mx) + __expf(h[2] - mx) + __expf(h[3] - mx);
    ssum += __shfl_xor(ssum, 1);
    ssum += __shfl_xor(ssum, 2);
    ssum += __shfl_xor(ssum, 4);
    ssum += __shfl_xor(ssum, 8);
    float lg = __logf(ssum);
    if (g == 0) {
        float4 o1 = make_float4(h[0], h[1], h[2], h[3]);
        *(float4*)&out[(size_t)n * 64 + c0] = o1;
        float4 o2 = make_float4(h[0] - mx - lg, h[1] - mx - lg, h[2] - mx - lg, h[3] - mx - lg);
        *(float4*)&out[(size_t)(N + n) * 64 + c0] = o2;
    }
}

// ---------------------------------------------------------------------------
extern "C" void kernel_launch(void* const* d_in, const int* in_sizes, int n_in,
                              void* d_out, int out_size, void* d_ws, size_t ws_size,
                              hipStream_t stream)
{
    const float* x    = (const float*)d_in[0];
    const int*   ei   = (const int*)d_in[1];
    const float* Wl1  = (const float*)d_in[2];
    const float* Wr1  = (const float*)d_in[3];
    const float* att1 = (const float*)d_in[4];
    const float* b1   = (const float*)d_in[5];
    const float* Wl2  = (const float*)d_in[6];
    const float* Wr2  = (const float*)d_in[7];
    const float* att2 = (const float*)d_in[8];
    const float* b2   = (const float*)d_in[9];
    float* out = (float*)d_out;

    const int F = 256, HC = 256, OUT = 64;
    const int E = in_sizes[1] / 2;
    const int N = in_sizes[0] / F;

    const int* e_src = ei;
    const int* e_dst = ei + E;

    // ---- workspace layout ----
    ushort* xb   = (ushort*)d_ws;                    // N*256
    ushort* wl1t = xb + (size_t)N * 256;             // 256x256 (Wt[N][K])
    ushort* wr1t = wl1t + 256 * 256;
    ushort* wl2t = wr1t + 256 * 256;                 // 64x256
    ushort* wr2t = wl2t + 64 * 256;
    ushort* xl1b = wr2t + 64 * 256;                  // N*256
    ushort* xr1b = xl1b + (size_t)N * 256;           // N*256
    ushort* h1b  = xr1b + (size_t)N * 256;           // N*256
    ushort* xl2b = h1b + (size_t)N * 256;            // N*64
    ushort* xr2b = xl2b + (size_t)N * 64;            // N*64
    int* offsets  = (int*)(xr2b + (size_t)N * 64);   // N+1
    int* cursor   = offsets + (N + 1);               // N+1
    int* counts   = cursor + (N + 1);                // N
    int* chunkoff = counts + N;                      // <=64+1
    int* csr_src  = chunkoff + 66;                   // E

    const int nchunks = (N + 1023) / 1024;

    // ---- dtype prep ----
    int tot = N * 256;
    k_cast_bf16<<<(tot / 4 + 255) / 256, 256, 0, stream>>>(x, xb, tot);
    k_tcast<<<(256 * 256 + 255) / 256, 256, 0, stream>>>(Wl1, wl1t, 256, 256);
    k_tcast<<<(256 * 256 + 255) / 256, 256, 0, stream>>>(Wr1, wr1t, 256, 256);
    k_tcast<<<(256 * 64 + 255) / 256, 256, 0, stream>>>(Wl2, wl2t, 256, 64);
    k_tcast<<<(256 * 64 + 255) / 256, 256, 0, stream>>>(Wr2, wr2t, 256, 64);

    // ---- CSR build ----
    hipMemsetAsync(counts, 0, (size_t)N * sizeof(int), stream);
    k_count<<<(E + 255) / 256, 256, 0, stream>>>(e_dst, E, counts);
    k_chunksum<<<nchunks, 256, 0, stream>>>(counts, N, chunkoff);
    k_scanchunk<<<1, 64, 0, stream>>>(chunkoff, nchunks);
    k_scanwrite<<<nchunks, 256, 0, stream>>>(counts, N, chunkoff, offsets, cursor);
    k_fill<<<(E + 255) / 256, 256, 0, stream>>>(e_src, e_dst, E, cursor, csr_src);

    // ---- layer 1 ----
    gemm_bf16<128, 128><<<dim3(HC / 128, (N + 127) / 128), 256, 0, stream>>>(xb, wl1t, xl1b, N, HC, F);
    gemm_bf16<128, 128><<<dim3(HC / 128, (N + 127) / 128), 256, 0, stream>>>(xb, wr1t, xr1b, N, HC, F);
    agg1<<<(N + 3) / 4, 256, 0, stream>>>(xl1b, xr1b, att1, b1, offsets, csr_src, h1b, N);

    // ---- layer 2 ----
    gemm_bf16<256, 64><<<dim3(OUT / 64, (N + 255) / 256), 256, 0, stream>>>(h1b, wl2t, xl2b, N, OUT, HC);
    gemm_bf16<256, 64><<<dim3(OUT / 64, (N + 255) / 256), 256, 0, stream>>>(h1b, wr2t, xr2b, N, OUT, HC);
    agg2<<<(N + 3) / 4, 256, 0, stream>>>(xl2b, xr2b, att2, b2, offsets, csr_src, out, N);
}

// Round 4
// 374.879 us; speedup vs baseline: 1.9091x; 1.1166x over previous
//
#include <hip/hip_runtime.h>
#include <hip/hip_bf16.h>
#include <math.h>

#define NEG_SLOPE 0.2f

typedef __attribute__((ext_vector_type(8))) short short8;
typedef __attribute__((ext_vector_type(4))) float floatx4;

__device__ inline ushort f2b(float f) {
    __hip_bfloat16 b = __float2bfloat16(f);
    return *(ushort*)&b;
}
__device__ inline float b2f(ushort u) {
    union { unsigned int i; float f; } c;
    c.i = ((unsigned int)u) << 16;
    return c.f;
}

// ---------------------------------------------------------------------------
// bf16 MFMA GEMM: C[M,N] = A[M,K] @ Bt[N,K]^T. A is fp32 or bf16 (templated,
// converted during LDS staging). Bt/C bf16 row-major. 256 threads = 4 waves,
// each wave a 64x64 tile via 4x4 16x16x32 MFMAs, BK=32.
// ---------------------------------------------------------------------------
template<int BM, int BN, typename AT>
__global__ __launch_bounds__(256) void gemm_bf16(const AT* __restrict__ A,
                                                 const ushort* __restrict__ Bt,
                                                 ushort* __restrict__ C,
                                                 int M, int N, int K)
{
    constexpr int SA = 40;                       // row stride in LDS (pad 8 bf16)
    __shared__ ushort As[BM * SA];
    __shared__ ushort Bs[BN * SA];
    const int tid = threadIdx.x;
    const int w = tid >> 6, lane = tid & 63;
    const int mw = (w & 1) * 64;
    const int nw = (w >> 1) * 64;
    const int m0 = blockIdx.y * BM;
    const int n0 = blockIdx.x * BN;
    const int lm = lane & 15;
    const int kg = lane >> 4;

    floatx4 acc[4][4];
#pragma unroll
    for (int i = 0; i < 4; ++i)
#pragma unroll
        for (int j = 0; j < 4; ++j) acc[i][j] = (floatx4)0.f;

    for (int k0 = 0; k0 < K; k0 += 32) {
#pragma unroll
        for (int it = 0; it < BM / 64; ++it) {
            int idx = it * 256 + tid;
            int row = idx >> 2, kc = idx & 3;
            int grow = m0 + row;
            if (grow >= M) grow = M - 1;
            if constexpr (sizeof(AT) == 4) {     // fp32 A: convert while staging
                float4 f0 = *(const float4*)&A[(size_t)grow * K + k0 + kc * 8];
                float4 f1 = *(const float4*)&A[(size_t)grow * K + k0 + kc * 8 + 4];
                ushort* d = &As[row * SA + kc * 8];
                d[0] = f2b(f0.x); d[1] = f2b(f0.y); d[2] = f2b(f0.z); d[3] = f2b(f0.w);
                d[4] = f2b(f1.x); d[5] = f2b(f1.y); d[6] = f2b(f1.z); d[7] = f2b(f1.w);
            } else {
                short8 v = *(const short8*)&A[(size_t)grow * K + k0 + kc * 8];
                *(short8*)&As[row * SA + kc * 8] = v;
            }
        }
#pragma unroll
        for (int it = 0; it < BN / 64; ++it) {
            int idx = it * 256 + tid;
            int row = idx >> 2, kc = idx & 3;
            short8 v = *(const short8*)&Bt[(size_t)(n0 + row) * K + k0 + kc * 8];
            *(short8*)&Bs[row * SA + kc * 8] = v;
        }
        __syncthreads();
        short8 a[4], b[4];
#pragma unroll
        for (int i = 0; i < 4; ++i)
            a[i] = *(const short8*)&As[(mw + i * 16 + lm) * SA + kg * 8];
#pragma unroll
        for (int j = 0; j < 4; ++j)
            b[j] = *(const short8*)&Bs[(nw + j * 16 + lm) * SA + kg * 8];
#pragma unroll
        for (int i = 0; i < 4; ++i)
#pragma unroll
            for (int j = 0; j < 4; ++j)
                acc[i][j] = __builtin_amdgcn_mfma_f32_16x16x32_bf16(a[i], b[j], acc[i][j], 0, 0, 0);
        __syncthreads();
    }

#pragma unroll
    for (int i = 0; i < 4; ++i) {
        int rbase = m0 + mw + i * 16 + (lane >> 4) * 4;
#pragma unroll
        for (int j = 0; j < 4; ++j) {
            int col = n0 + nw + j * 16 + lm;
#pragma unroll
            for (int r = 0; r < 4; ++r) {
                int row = rbase + r;
                if (row < M) C[(size_t)row * N + col] = f2b(acc[i][j][r]);
            }
        }
    }
}

// ---------------------------------------------------------------------------
// W[K,N] fp32 -> Wt[N,K] bf16 (tiny)
// ---------------------------------------------------------------------------
__global__ void k_tcast(const float* __restrict__ W, ushort* __restrict__ Wt, int K, int N)
{
    int i = blockIdx.x * blockDim.x + threadIdx.x;
    if (i < K * N) {
        int k = i / N, n = i % N;
        Wt[(size_t)n * K + k] = f2b(W[i]);
    }
}

// ---------------------------------------------------------------------------
// CSR build
// ---------------------------------------------------------------------------
__global__ void k_count(const int* __restrict__ dst, int E, int* __restrict__ counts)
{
    int i = blockIdx.x * blockDim.x + threadIdx.x;
    if (i < E) atomicAdd(&counts[dst[i]], 1);
}

__global__ void k_chunksum(const int* __restrict__ counts, int N, int* __restrict__ chunk)
{
    __shared__ int sm[256];
    const int t = threadIdx.x;
    const int base = blockIdx.x * 1024;
    int s = 0;
    for (int i = t; i < 1024; i += 256) {
        int idx = base + i;
        s += (idx < N) ? counts[idx] : 0;
    }
    sm[t] = s;
    __syncthreads();
    for (int off = 128; off; off >>= 1) {
        if (t < off) sm[t] += sm[t + off];
        __syncthreads();
    }
    if (t == 0) chunk[blockIdx.x] = sm[0];
}

__global__ void k_scanchunk(int* __restrict__ chunk, int nchunks)
{
    if (blockIdx.x == 0 && threadIdx.x == 0) {
        int run = 0;
        for (int i = 0; i < nchunks; ++i) {
            int c = chunk[i];
            chunk[i] = run;
            run += c;
        }
        chunk[nchunks] = run;
    }
}

__global__ void k_scanwrite(const int* __restrict__ counts, int N,
                            const int* __restrict__ chunk,
                            int* __restrict__ offsets, int* __restrict__ cursor)
{
    __shared__ int sm[256];
    const int t = threadIdx.x;
    const int base = blockIdx.x * 1024 + t * 4;
    int v[4];
    int s = 0;
#pragma unroll
    for (int i = 0; i < 4; ++i) {
        v[i] = (base + i < N) ? counts[base + i] : 0;
        s += v[i];
    }
    sm[t] = s;
    __syncthreads();
    for (int off = 1; off < 256; off <<= 1) {
        int y = (t >= off) ? sm[t - off] : 0;
        __syncthreads();
        sm[t] += y;
        __syncthreads();
    }
    int run = chunk[blockIdx.x] + sm[t] - s;
#pragma unroll
    for (int i = 0; i < 4; ++i) {
        if (base + i < N) {
            offsets[base + i] = run;
            cursor[base + i] = run;
        }
        run += v[i];
    }
    if (blockIdx.x == 0 && t == 0) offsets[N] = chunk[gridDim.x];
}

__global__ void k_fill(const int* __restrict__ src, const int* __restrict__ dst,
                       int E, int* __restrict__ cursor, int* __restrict__ csr_src)
{
    int i = blockIdx.x * blockDim.x + threadIdx.x;
    if (i < E) {
        int d = dst[i];
        int pos = atomicAdd(&cursor[d], 1);
        csr_src[pos] = src[i];
    }
}

// ---------------------------------------------------------------------------
// Layer-1 aggregation: one wave per node, 2 edge-slots x 32 lanes.
// Lane owns 8 consecutive channels of one head (ushort8 gather = 16B/lane).
// Logit reduce = 2 shuffles over the 4-lane channel group. Single-exp
// branchless online softmax; slot states merged at the end. xlr layout:
// row stride 512, xl at +0, xr at +256.
// ---------------------------------------------------------------------------
__global__ __launch_bounds__(256) void agg1(const ushort* __restrict__ xlr,
                                            const float* __restrict__ att,
                                            const float* __restrict__ bias,
                                            const int* __restrict__ offsets,
                                            const int* __restrict__ csr_src,
                                            ushort* __restrict__ h1, int N)
{
    const int wave = blockIdx.x * 4 + (threadIdx.x >> 6);
    const int lane = threadIdx.x & 63;
    if (wave >= N) return;
    const int n = wave;
    const int g = lane >> 5;                       // edge slot 0/1
    const int sl = lane & 31;
    const int elem = (sl >> 2) * 32 + (sl & 3) * 8; // head*32 + quad*8

    float attv[8], xrv[8];
    {
        short8 xr8 = *(const short8*)&xlr[(size_t)n * 512 + 256 + elem];
#pragma unroll
        for (int j = 0; j < 8; ++j) {
            attv[j] = att[elem + j];
            xrv[j] = b2f((ushort)xr8[j]);
        }
    }
    float m = -1e30f, l = 0.f;
    float acc[8] = {0.f, 0.f, 0.f, 0.f, 0.f, 0.f, 0.f, 0.f};

    const int beg = offsets[n], end = offsets[n + 1];
    short8 xv;
    {
        int k = beg + g;
        if (k < end) xv = *(const short8*)&xlr[(size_t)csr_src[k] * 512 + elem];
    }
    for (int kb = beg; kb < end; kb += 2) {
        const int kk = kb + g;
        short8 cur = xv;
        {
            int kn = kk + 2;
            if (kn < end) xv = *(const short8*)&xlr[(size_t)csr_src[kn] * 512 + elem];
        }
        if (kk < end) {
            float xlv[8];
#pragma unroll
            for (int j = 0; j < 8; ++j) xlv[j] = b2f((ushort)cur[j]);
            float u = 0.f;
#pragma unroll
            for (int j = 0; j < 8; ++j) {
                float t = xlv[j] + xrv[j];
                t = fmaxf(t, NEG_SLOPE * t);       // leaky_relu, slope<1
                u = fmaf(t, attv[j], u);
            }
            u += __shfl_xor(u, 1);                 // 4-lane channel-group reduce
            u += __shfl_xor(u, 2);
            // single-exp branchless online softmax update
            float e = __expf(-fabsf(u - m));
            bool keep = (m >= u);
            float sc = keep ? 1.f : e;             // rescale of old state
            float p  = keep ? e : 1.f;             // weight of new edge
            m = fmaxf(m, u);
#pragma unroll
            for (int j = 0; j < 8; ++j) acc[j] = fmaf(acc[j], sc, p * xlv[j]);
            l = fmaf(l, sc, p);
        }
    }
    // merge the two slot states (butterfly over lane^32)
    {
        float mo = __shfl_xor(m, 32);
        float lo = __shfl_xor(l, 32);
        float nm = fmaxf(m, mo);
        float ea = __expf(m - nm);
        float eb = __expf(mo - nm);
#pragma unroll
        for (int j = 0; j < 8; ++j) {
            float ao = __shfl_xor(acc[j], 32);
            acc[j] = acc[j] * ea + ao * eb;
        }
        l = l * ea + lo * eb;
    }
    if (g == 0) {
        float rl = 1.f / (l + 1e-16f);
        short8 o;
#pragma unroll
        for (int j = 0; j < 8; ++j) {
            float v = fmaf(acc[j], rl, bias[elem + j]);
            o[j] = (short)f2b(fmaxf(v, 0.f));
        }
        *(short8*)&h1[(size_t)n * 256 + elem] = o;
    }
}

// ---------------------------------------------------------------------------
// Layer-2 aggregation: one wave per node, 4 edge-slots x 16 lanes, 4 ch/lane.
// xlr2 layout: row stride 128, xl at +0, xr at +64. Single-exp online update,
// associative merge across slots, fused bias + log_softmax epilogue.
// ---------------------------------------------------------------------------
__global__ __launch_bounds__(256) void agg2(const ushort* __restrict__ xlr,
                                            const float* __restrict__ att,
                                            const float* __restrict__ bias,
                                            const int* __restrict__ offsets,
                                            const int* __restrict__ csr_src,
                                            float* __restrict__ out, int N)
{
    const int wave = blockIdx.x * 4 + (threadIdx.x >> 6);
    const int lane = threadIdx.x & 63;
    if (wave >= N) return;
    const int n = wave;
    const int g = lane >> 4;
    const int c0 = (lane & 15) * 4;

    const float4 attv = *(const float4*)&att[c0];
    ushort4 xr4 = *(const ushort4*)&xlr[(size_t)n * 128 + 64 + c0];
    float xrv[4] = {b2f(xr4.x), b2f(xr4.y), b2f(xr4.z), b2f(xr4.w)};

    float m = -1e30f, l = 0.f;
    float acc[4] = {0.f, 0.f, 0.f, 0.f};

    const int beg = offsets[n], end = offsets[n + 1];
    for (int kb = beg; kb < end; kb += 4) {
        int k = kb + g;
        if (k < end) {
            int s = csr_src[k];
            ushort4 xv = *(const ushort4*)&xlr[(size_t)s * 128 + c0];
            float xlv[4] = {b2f(xv.x), b2f(xv.y), b2f(xv.z), b2f(xv.w)};
            float u = 0.f;
#pragma unroll
            for (int j = 0; j < 4; ++j) {
                float t = xlv[j] + xrv[j];
                t = fmaxf(t, NEG_SLOPE * t);
                u = fmaf(t, ((const float*)&attv)[j], u);
            }
            u += __shfl_xor(u, 1);
            u += __shfl_xor(u, 2);
            u += __shfl_xor(u, 4);
            u += __shfl_xor(u, 8);
            float e = __expf(-fabsf(u - m));
            bool keep = (m >= u);
            float sc = keep ? 1.f : e;
            float p  = keep ? e : 1.f;
            m = fmaxf(m, u);
#pragma unroll
            for (int j = 0; j < 4; ++j) acc[j] = fmaf(acc[j], sc, p * xlv[j]);
            l = fmaf(l, sc, p);
        }
    }
#pragma unroll
    for (int off = 16; off <= 32; off <<= 1) {
        float mo = __shfl_xor(m, off);
        float lo = __shfl_xor(l, off);
        float ao[4];
#pragma unroll
        for (int j = 0; j < 4; ++j) ao[j] = __shfl_xor(acc[j], off);
        float nm = fmaxf(m, mo);
        float sa = __expf(m - nm);
        float sb = __expf(mo - nm);
#pragma unroll
        for (int j = 0; j < 4; ++j) acc[j] = acc[j] * sa + ao[j] * sb;
        l = l * sa + lo * sb;
        m = nm;
    }
    float rl = 1.f / (l + 1e-16f);
    const float4 bv = *(const float4*)&bias[c0];
    float h[4];
#pragma unroll
    for (int j = 0; j < 4; ++j) h[j] = acc[j] * rl + ((const float*)&bv)[j];

    float mx = fmaxf(fmaxf(h[0], h[1]), fmaxf(h[2], h[3]));
    mx = fmaxf(mx, __shfl_xor(mx, 1));
    mx = fmaxf(mx, __shfl_xor(mx, 2));
    mx = fmaxf(mx, __shfl_xor(mx, 4));
    mx = fmaxf(mx, __shfl_xor(mx, 8));
    float ssum = __expf(h[0] - mx) + __expf(h[1] - mx) + __expf(h[2] - mx) + __expf(h[3] - mx);
    ssum += __shfl_xor(ssum, 1);
    ssum += __shfl_xor(ssum, 2);
    ssum += __shfl_xor(ssum, 4);
    ssum += __shfl_xor(ssum, 8);
    float lg = __logf(ssum);
    if (g == 0) {
        float4 o1 = make_float4(h[0], h[1], h[2], h[3]);
        *(float4*)&out[(size_t)n * 64 + c0] = o1;
        float4 o2 = make_float4(h[0] - mx - lg, h[1] - mx - lg, h[2] - mx - lg, h[3] - mx - lg);
        *(float4*)&out[(size_t)(N + n) * 64 + c0] = o2;
    }
}

// ---------------------------------------------------------------------------
extern "C" void kernel_launch(void* const* d_in, const int* in_sizes, int n_in,
                              void* d_out, int out_size, void* d_ws, size_t ws_size,
                              hipStream_t stream)
{
    const float* x    = (const float*)d_in[0];
    const int*   ei   = (const int*)d_in[1];
    const float* Wl1  = (const float*)d_in[2];
    const float* Wr1  = (const float*)d_in[3];
    const float* att1 = (const float*)d_in[4];
    const float* b1   = (const float*)d_in[5];
    const float* Wl2  = (const float*)d_in[6];
    const float* Wr2  = (const float*)d_in[7];
    const float* att2 = (const float*)d_in[8];
    const float* b2   = (const float*)d_in[9];
    float* out = (float*)d_out;

    const int F = 256;
    const int E = in_sizes[1] / 2;
    const int N = in_sizes[0] / F;

    const int* e_src = ei;
    const int* e_dst = ei + E;

    // ---- workspace layout ----
    ushort* wlr1t = (ushort*)d_ws;                   // [512][256]  (Wl1|Wr1)^T
    ushort* wlr2t = wlr1t + 512 * 256;               // [128][256]  (Wl2|Wr2)^T
    ushort* xlr1  = wlr2t + 128 * 256;               // [N][512]  xl|xr
    ushort* h1b   = xlr1 + (size_t)N * 512;          // [N][256]
    ushort* xlr2  = h1b + (size_t)N * 256;           // [N][128]  xl|xr
    int* offsets  = (int*)(xlr2 + (size_t)N * 128);  // N+1
    int* cursor   = offsets + (N + 1);               // N+1
    int* counts   = cursor + (N + 1);                // N
    int* chunkoff = counts + N;                      // <=64+1
    int* csr_src  = chunkoff + 66;                   // E

    const int nchunks = (N + 1023) / 1024;

    // ---- weight prep (tiny) ----
    k_tcast<<<(256 * 256 + 255) / 256, 256, 0, stream>>>(Wl1, wlr1t, 256, 256);
    k_tcast<<<(256 * 256 + 255) / 256, 256, 0, stream>>>(Wr1, wlr1t + 256 * 256, 256, 256);
    k_tcast<<<(256 * 64 + 255) / 256, 256, 0, stream>>>(Wl2, wlr2t, 256, 64);
    k_tcast<<<(256 * 64 + 255) / 256, 256, 0, stream>>>(Wr2, wlr2t + 64 * 256, 256, 64);

    // ---- CSR build ----
    hipMemsetAsync(counts, 0, (size_t)N * sizeof(int), stream);
    k_count<<<(E + 255) / 256, 256, 0, stream>>>(e_dst, E, counts);
    k_chunksum<<<nchunks, 256, 0, stream>>>(counts, N, chunkoff);
    k_scanchunk<<<1, 64, 0, stream>>>(chunkoff, nchunks);
    k_scanwrite<<<nchunks, 256, 0, stream>>>(counts, N, chunkoff, offsets, cursor);
    k_fill<<<(E + 255) / 256, 256, 0, stream>>>(e_src, e_dst, E, cursor, csr_src);

    // ---- layer 1: fused (xl|xr) GEMM from fp32 x, then aggregate ----
    gemm_bf16<128, 128, float><<<dim3(4, (N + 127) / 128), 256, 0, stream>>>(x, wlr1t, xlr1, N, 512, F);
    agg1<<<(N + 3) / 4, 256, 0, stream>>>(xlr1, att1, b1, offsets, csr_src, h1b, N);

    // ---- layer 2: fused (xl|xr) GEMM from bf16 h1, then aggregate ----
    gemm_bf16<128, 128, ushort><<<dim3(1, (N + 127) / 128), 256, 0, stream>>>(h1b, wlr2t, xlr2, N, 128, 256);
    agg2<<<(N + 3) / 4, 256, 0, stream>>>(xlr2, att2, b2, offsets, csr_src, out, N);
}

// Round 5
// 358.136 us; speedup vs baseline: 1.9984x; 1.0467x over previous
//
#include <hip/hip_runtime.h>
#include <hip/hip_bf16.h>
#include <math.h>

#define NEG_SLOPE 0.2f

typedef __attribute__((ext_vector_type(8))) short short8;
typedef __attribute__((ext_vector_type(4))) float floatx4;
typedef __attribute__((ext_vector_type(2))) float floatx2;

__device__ inline ushort f2b(float f) {
    __hip_bfloat16 b = __float2bfloat16(f);
    return *(ushort*)&b;
}
__device__ inline float b2f(ushort u) {
    union { unsigned int i; float f; } c;
    c.i = ((unsigned int)u) << 16;
    return c.f;
}
// dword holding 2 bf16 (lo, hi) -> floatx2
__device__ inline floatx2 bf2x2(unsigned int d) {
    union { unsigned int i; float f; } lo, hi;
    lo.i = d << 16;
    hi.i = d & 0xffff0000u;
    floatx2 r = {lo.f, hi.f};
    return r;
}

// ---------------------------------------------------------------------------
// bf16 MFMA GEMM: C[M,N] = A[M,K] @ Bt[N,K]^T. A fp32 or bf16 (templated,
// converted during LDS staging). 256 threads = 4 waves.
// BN=128: waves in 2x2 of 64x64 (acc[4][4]). BN=64: waves in 4x1 of 32x64
// (acc[2][4]) so small-N GEMMs get 2x the blocks.
// ---------------------------------------------------------------------------
template<int BM, int BN, typename AT>
__global__ __launch_bounds__(256) void gemm_bf16(const AT* __restrict__ A,
                                                 const ushort* __restrict__ Bt,
                                                 ushort* __restrict__ C,
                                                 int M, int N, int K)
{
    constexpr int SA = 40;                       // LDS row stride (pad 8 bf16)
    constexpr int WTM = (BN == 64) ? 32 : 64;    // wave tile M
    constexpr int WM  = BM / WTM;                // waves along M
    constexpr int IT  = WTM / 16;                // i-tiles per wave
    constexpr int JT  = 4;                       // j-tiles (wave tile N = 64)
    __shared__ ushort As[BM * SA];
    __shared__ ushort Bs[BN * SA];
    const int tid = threadIdx.x;
    const int w = tid >> 6, lane = tid & 63;
    const int mw = (w % WM) * WTM;
    const int nw = (w / WM) * 64;
    const int m0 = blockIdx.y * BM;
    const int n0 = blockIdx.x * BN;
    const int lm = lane & 15;
    const int kg = lane >> 4;

    floatx4 acc[IT][JT];
#pragma unroll
    for (int i = 0; i < IT; ++i)
#pragma unroll
        for (int j = 0; j < JT; ++j) acc[i][j] = (floatx4)0.f;

    for (int k0 = 0; k0 < K; k0 += 32) {
#pragma unroll
        for (int it = 0; it < BM / 64; ++it) {
            int idx = it * 256 + tid;
            int row = idx >> 2, kc = idx & 3;
            int grow = m0 + row;
            if (grow >= M) grow = M - 1;
            if constexpr (sizeof(AT) == 4) {     // fp32 A: convert while staging
                float4 f0 = *(const float4*)&A[(size_t)grow * K + k0 + kc * 8];
                float4 f1 = *(const float4*)&A[(size_t)grow * K + k0 + kc * 8 + 4];
                ushort* d = &As[row * SA + kc * 8];
                d[0] = f2b(f0.x); d[1] = f2b(f0.y); d[2] = f2b(f0.z); d[3] = f2b(f0.w);
                d[4] = f2b(f1.x); d[5] = f2b(f1.y); d[6] = f2b(f1.z); d[7] = f2b(f1.w);
            } else {
                short8 v = *(const short8*)&A[(size_t)grow * K + k0 + kc * 8];
                *(short8*)&As[row * SA + kc * 8] = v;
            }
        }
#pragma unroll
        for (int it = 0; it < BN / 64; ++it) {
            int idx = it * 256 + tid;
            int row = idx >> 2, kc = idx & 3;
            short8 v = *(const short8*)&Bt[(size_t)(n0 + row) * K + k0 + kc * 8];
            *(short8*)&Bs[row * SA + kc * 8] = v;
        }
        __syncthreads();
        short8 a[IT], b[JT];
#pragma unroll
        for (int i = 0; i < IT; ++i)
            a[i] = *(const short8*)&As[(mw + i * 16 + lm) * SA + kg * 8];
#pragma unroll
        for (int j = 0; j < JT; ++j)
            b[j] = *(const short8*)&Bs[(nw + j * 16 + lm) * SA + kg * 8];
#pragma unroll
        for (int i = 0; i < IT; ++i)
#pragma unroll
            for (int j = 0; j < JT; ++j)
                acc[i][j] = __builtin_amdgcn_mfma_f32_16x16x32_bf16(a[i], b[j], acc[i][j], 0, 0, 0);
        __syncthreads();
    }

#pragma unroll
    for (int i = 0; i < IT; ++i) {
        int rbase = m0 + mw + i * 16 + (lane >> 4) * 4;
#pragma unroll
        for (int j = 0; j < JT; ++j) {
            int col = n0 + nw + j * 16 + lm;
#pragma unroll
            for (int r = 0; r < 4; ++r) {
                int row = rbase + r;
                if (row < M) C[(size_t)row * N + col] = f2b(acc[i][j][r]);
            }
        }
    }
}

// ---------------------------------------------------------------------------
// Fused prep: 4 weight transposes+casts, plus degree count (independent work,
// one dispatch). counts must be zeroed before this kernel (stream-ordered).
// ---------------------------------------------------------------------------
__global__ void k_prep(const float* __restrict__ Wl1, const float* __restrict__ Wr1,
                       const float* __restrict__ Wl2, const float* __restrict__ Wr2,
                       ushort* __restrict__ wlr1t, ushort* __restrict__ wlr2t,
                       const int* __restrict__ dst, int E, int* __restrict__ counts)
{
    const int b = blockIdx.x;
    const int t = threadIdx.x;
    if (b < 640) {                               // 163840 weight elements
        int i = b * 256 + t;
        if (i < 65536) {
            int k = i >> 8, n = i & 255;
            wlr1t[n * 256 + k] = f2b(Wl1[i]);
        } else if (i < 131072) {
            int j = i - 65536;
            int k = j >> 8, n = j & 255;
            wlr1t[65536 + n * 256 + k] = f2b(Wr1[j]);
        } else if (i < 147456) {
            int j = i - 131072;
            int k = j >> 6, n = j & 63;
            wlr2t[n * 256 + k] = f2b(Wl2[j]);
        } else {
            int j = i - 147456;
            int k = j >> 6, n = j & 63;
            wlr2t[16384 + n * 256 + k] = f2b(Wr2[j]);
        }
    } else {
        int i = (b - 640) * 256 + t;
        if (i < E) atomicAdd(&counts[dst[i]], 1);
    }
}

// ---------------------------------------------------------------------------
// CSR build (scan + fill)
// ---------------------------------------------------------------------------
__global__ void k_chunksum(const int* __restrict__ counts, int N, int* __restrict__ chunk)
{
    __shared__ int sm[256];
    const int t = threadIdx.x;
    const int base = blockIdx.x * 1024;
    int s = 0;
    for (int i = t; i < 1024; i += 256) {
        int idx = base + i;
        s += (idx < N) ? counts[idx] : 0;
    }
    sm[t] = s;
    __syncthreads();
    for (int off = 128; off; off >>= 1) {
        if (t < off) sm[t] += sm[t + off];
        __syncthreads();
    }
    if (t == 0) chunk[blockIdx.x] = sm[0];
}

__global__ void k_scanchunk(int* __restrict__ chunk, int nchunks)
{
    if (blockIdx.x == 0 && threadIdx.x == 0) {
        int run = 0;
        for (int i = 0; i < nchunks; ++i) {
            int c = chunk[i];
            chunk[i] = run;
            run += c;
        }
        chunk[nchunks] = run;
    }
}

__global__ void k_scanwrite(const int* __restrict__ counts, int N,
                            const int* __restrict__ chunk,
                            int* __restrict__ offsets, int* __restrict__ cursor)
{
    __shared__ int sm[256];
    const int t = threadIdx.x;
    const int base = blockIdx.x * 1024 + t * 4;
    int v[4];
    int s = 0;
#pragma unroll
    for (int i = 0; i < 4; ++i) {
        v[i] = (base + i < N) ? counts[base + i] : 0;
        s += v[i];
    }
    sm[t] = s;
    __syncthreads();
    for (int off = 1; off < 256; off <<= 1) {
        int y = (t >= off) ? sm[t - off] : 0;
        __syncthreads();
        sm[t] += y;
        __syncthreads();
    }
    int run = chunk[blockIdx.x] + sm[t] - s;
#pragma unroll
    for (int i = 0; i < 4; ++i) {
        if (base + i < N) {
            offsets[base + i] = run;
            cursor[base + i] = run;
        }
        run += v[i];
    }
    if (blockIdx.x == 0 && t == 0) offsets[N] = chunk[gridDim.x];
}

__global__ void k_fill(const int* __restrict__ src, const int* __restrict__ dst,
                       int E, int* __restrict__ cursor, int* __restrict__ csr_src)
{
    int i = blockIdx.x * blockDim.x + threadIdx.x;
    if (i < E) {
        int d = dst[i];
        int pos = atomicAdd(&cursor[d], 1);
        csr_src[pos] = src[i];
    }
}

// ---------------------------------------------------------------------------
// Layer-1 aggregation: one wave per node, 2 edge-slots x 32 lanes, 8 ch/lane.
// Packed-fp32 (float2) elementwise math -> v_pk_* issues. Single-exp online
// softmax; slot merge at end. xlr: row stride 512 (xl at +0, xr at +256).
// ---------------------------------------------------------------------------
__global__ __launch_bounds__(256) void agg1(const ushort* __restrict__ xlr,
                                            const float* __restrict__ att,
                                            const float* __restrict__ bias,
                                            const int* __restrict__ offsets,
                                            const int* __restrict__ csr_src,
                                            ushort* __restrict__ h1, int N)
{
    const int wave = blockIdx.x * 4 + (threadIdx.x >> 6);
    const int lane = threadIdx.x & 63;
    if (wave >= N) return;
    const int n = wave;
    const int g = lane >> 5;                        // edge slot 0/1
    const int sl = lane & 31;
    const int elem = (sl >> 2) * 32 + (sl & 3) * 8; // head*32 + quad*8

    floatx2 attv2[4], xrv2[4];
    {
        uint4 xr8 = *(const uint4*)&xlr[(size_t)n * 512 + 256 + elem];
        unsigned int xw[4] = {xr8.x, xr8.y, xr8.z, xr8.w};
#pragma unroll
        for (int i = 0; i < 4; ++i) {
            attv2[i] = *(const floatx2*)&att[elem + 2 * i];
            xrv2[i] = bf2x2(xw[i]);
        }
    }
    float m = -1e30f, l = 0.f;
    floatx2 acc2[4] = {(floatx2)0.f, (floatx2)0.f, (floatx2)0.f, (floatx2)0.f};

    const int beg = offsets[n], end = offsets[n + 1];
    if (beg < end) {
        uint4 xv;
        {
            int k0 = beg + g;
            int ks = (k0 < end) ? k0 : end - 1;
            xv = *(const uint4*)&xlr[(size_t)csr_src[ks] * 512 + elem];
        }
        for (int kb = beg; kb < end; kb += 2) {
            const int kk = kb + g;
            uint4 cur = xv;
            {
                int kn = kk + 2;
                int ks = (kn < end) ? kn : end - 1;
                xv = *(const uint4*)&xlr[(size_t)csr_src[ks] * 512 + elem];
            }
            if (kk < end) {
                unsigned int cw[4] = {cur.x, cur.y, cur.z, cur.w};
                floatx2 xl2[4];
                floatx2 u2 = (floatx2)0.f;
#pragma unroll
                for (int i = 0; i < 4; ++i) {
                    xl2[i] = bf2x2(cw[i]);
                    floatx2 t = xl2[i] + xrv2[i];
                    t = __builtin_elementwise_max(t, t * NEG_SLOPE);  // leaky
                    u2 += t * attv2[i];
                }
                float u = u2.x + u2.y;
                u += __shfl_xor(u, 1);              // 4-lane channel-group reduce
                u += __shfl_xor(u, 2);
                // single-exp branchless online softmax update
                float e = __expf(-fabsf(u - m));
                bool kp = (m >= u);
                float sc = kp ? 1.f : e;
                float p  = kp ? e : 1.f;
                m = fmaxf(m, u);
#pragma unroll
                for (int i = 0; i < 4; ++i) acc2[i] = acc2[i] * sc + xl2[i] * p;
                l = fmaf(l, sc, p);
            }
        }
    }
    // merge the two slot states (butterfly over lane^32)
    {
        float mo = __shfl_xor(m, 32);
        float lo = __shfl_xor(l, 32);
        float nm = fmaxf(m, mo);
        float ea = __expf(m - nm);
        float eb = __expf(mo - nm);
#pragma unroll
        for (int i = 0; i < 4; ++i) {
            floatx2 ao = {__shfl_xor(acc2[i].x, 32), __shfl_xor(acc2[i].y, 32)};
            acc2[i] = acc2[i] * ea + ao * eb;
        }
        l = l * ea + lo * eb;
    }
    if (g == 0) {
        float rl = 1.f / (l + 1e-16f);
        short8 o;
#pragma unroll
        for (int i = 0; i < 4; ++i) {
            float v0 = fmaf(acc2[i].x, rl, bias[elem + 2 * i]);
            float v1 = fmaf(acc2[i].y, rl, bias[elem + 2 * i + 1]);
            o[2 * i]     = (short)f2b(fmaxf(v0, 0.f));
            o[2 * i + 1] = (short)f2b(fmaxf(v1, 0.f));
        }
        *(short8*)&h1[(size_t)n * 256 + elem] = o;
    }
}

// ---------------------------------------------------------------------------
// Layer-2 aggregation: one wave per node, 4 edge-slots x 16 lanes, 4 ch/lane.
// Prefetched gather + packed-fp32 math. xlr2: row stride 128 (xl +0, xr +64).
// Single-exp online update, slot merge, fused bias + log_softmax epilogue.
// ---------------------------------------------------------------------------
__global__ __launch_bounds__(256) void agg2(const ushort* __restrict__ xlr,
                                            const float* __restrict__ att,
                                            const float* __restrict__ bias,
                                            const int* __restrict__ offsets,
                                            const int* __restrict__ csr_src,
                                            float* __restrict__ out, int N)
{
    const int wave = blockIdx.x * 4 + (threadIdx.x >> 6);
    const int lane = threadIdx.x & 63;
    if (wave >= N) return;
    const int n = wave;
    const int g = lane >> 4;
    const int c0 = (lane & 15) * 4;

    floatx2 attv2[2], xrv2[2];
    {
        uint2 xr4 = *(const uint2*)&xlr[(size_t)n * 128 + 64 + c0];
        attv2[0] = *(const floatx2*)&att[c0];
        attv2[1] = *(const floatx2*)&att[c0 + 2];
        xrv2[0] = bf2x2(xr4.x);
        xrv2[1] = bf2x2(xr4.y);
    }
    float m = -1e30f, l = 0.f;
    floatx2 acc2[2] = {(floatx2)0.f, (floatx2)0.f};

    const int beg = offsets[n], end = offsets[n + 1];
    if (beg < end) {
        uint2 xv;
        {
            int k0 = beg + g;
            int ks = (k0 < end) ? k0 : end - 1;
            xv = *(const uint2*)&xlr[(size_t)csr_src[ks] * 128 + c0];
        }
        for (int kb = beg; kb < end; kb += 4) {
            const int kk = kb + g;
            uint2 cur = xv;
            {
                int kn = kk + 4;
                int ks = (kn < end) ? kn : end - 1;
                xv = *(const uint2*)&xlr[(size_t)csr_src[ks] * 128 + c0];
            }
            if (kk < end) {
                floatx2 xl2[2];
                xl2[0] = bf2x2(cur.x);
                xl2[1] = bf2x2(cur.y);
                floatx2 u2 = (floatx2)0.f;
#pragma unroll
                for (int i = 0; i < 2; ++i) {
                    floatx2 t = xl2[i] + xrv2[i];
                    t = __builtin_elementwise_max(t, t * NEG_SLOPE);
                    u2 += t * attv2[i];
                }
                float u = u2.x + u2.y;
                u += __shfl_xor(u, 1);
                u += __shfl_xor(u, 2);
                u += __shfl_xor(u, 4);
                u += __shfl_xor(u, 8);
                float e = __expf(-fabsf(u - m));
                bool kp = (m >= u);
                float sc = kp ? 1.f : e;
                float p  = kp ? e : 1.f;
                m = fmaxf(m, u);
#pragma unroll
                for (int i = 0; i < 2; ++i) acc2[i] = acc2[i] * sc + xl2[i] * p;
                l = fmaf(l, sc, p);
            }
        }
    }
    // merge the 4 slot states
#pragma unroll
    for (int off = 16; off <= 32; off <<= 1) {
        float mo = __shfl_xor(m, off);
        float lo = __shfl_xor(l, off);
        float nm = fmaxf(m, mo);
        float sa = __expf(m - nm);
        float sb = __expf(mo - nm);
#pragma unroll
        for (int i = 0; i < 2; ++i) {
            floatx2 ao = {__shfl_xor(acc2[i].x, off), __shfl_xor(acc2[i].y, off)};
            acc2[i] = acc2[i] * sa + ao * sb;
        }
        l = l * sa + lo * sb;
        m = nm;
    }
    float rl = 1.f / (l + 1e-16f);
    float h[4];
    h[0] = acc2[0].x * rl + bias[c0];
    h[1] = acc2[0].y * rl + bias[c0 + 1];
    h[2] = acc2[1].x * rl + bias[c0 + 2];
    h[3] = acc2[1].y * rl + bias[c0 + 3];

    float mx = fmaxf(fmaxf(h[0], h[1]), fmaxf(h[2], h[3]));
    mx = fmaxf(mx, __shfl_xor(mx, 1));
    mx = fmaxf(mx, __shfl_xor(mx, 2));
    mx = fmaxf(mx, __shfl_xor(mx, 4));
    mx = fmaxf(mx, __shfl_xor(mx, 8));
    float ssum = __expf(h[0] - mx) + __expf(h[1] - mx) + __expf(h[2] - mx) + __expf(h[3] - mx);
    ssum += __shfl_xor(ssum, 1);
    ssum += __shfl_xor(ssum, 2);
    ssum += __shfl_xor(ssum, 4);
    ssum += __shfl_xor(ssum, 8);
    float lg = __logf(ssum);
    if (g == 0) {
        float4 o1 = make_float4(h[0], h[1], h[2], h[3]);
        *(float4*)&out[(size_t)n * 64 + c0] = o1;
        float4 o2 = make_float4(h[0] - mx - lg, h[1] - mx - lg, h[2] - mx - lg, h[3] - mx - lg);
        *(float4*)&out[(size_t)(N + n) * 64 + c0] = o2;
    }
}

// ---------------------------------------------------------------------------
extern "C" void kernel_launch(void* const* d_in, const int* in_sizes, int n_in,
                              void* d_out, int out_size, void* d_ws, size_t ws_size,
                              hipStream_t stream)
{
    const float* x    = (const float*)d_in[0];
    const int*   ei   = (const int*)d_in[1];
    const float* Wl1  = (const float*)d_in[2];
    const float* Wr1  = (const float*)d_in[3];
    const float* att1 = (const float*)d_in[4];
    const float* b1   = (const float*)d_in[5];
    const float* Wl2  = (const float*)d_in[6];
    const float* Wr2  = (const float*)d_in[7];
    const float* att2 = (const float*)d_in[8];
    const float* b2   = (const float*)d_in[9];
    float* out = (float*)d_out;

    const int F = 256;
    const int E = in_sizes[1] / 2;
    const int N = in_sizes[0] / F;

    const int* e_src = ei;
    const int* e_dst = ei + E;

    // ---- workspace layout ----
    ushort* wlr1t = (ushort*)d_ws;                   // [512][256]  (Wl1|Wr1)^T
    ushort* wlr2t = wlr1t + 512 * 256;               // [128][256]  (Wl2|Wr2)^T
    ushort* xlr1  = wlr2t + 128 * 256;               // [N][512]  xl|xr
    ushort* h1b   = xlr1 + (size_t)N * 512;          // [N][256]
    ushort* xlr2  = h1b + (size_t)N * 256;           // [N][128]  xl|xr
    int* offsets  = (int*)(xlr2 + (size_t)N * 128);  // N+1
    int* cursor   = offsets + (N + 1);               // N+1
    int* counts   = cursor + (N + 1);                // N
    int* chunkoff = counts + N;                      // <=64+1
    int* csr_src  = chunkoff + 66;                   // E

    const int nchunks = (N + 1023) / 1024;

    // ---- fused prep (weights cast/transpose + degree count) ----
    hipMemsetAsync(counts, 0, (size_t)N * sizeof(int), stream);
    k_prep<<<640 + (E + 255) / 256, 256, 0, stream>>>(Wl1, Wr1, Wl2, Wr2,
                                                      wlr1t, wlr2t, e_dst, E, counts);

    // ---- layer-1 GEMM (independent of CSR scan chain) ----
    gemm_bf16<128, 128, float><<<dim3(4, (N + 127) / 128), 256, 0, stream>>>(x, wlr1t, xlr1, N, 512, F);

    // ---- CSR scan + fill ----
    k_chunksum<<<nchunks, 256, 0, stream>>>(counts, N, chunkoff);
    k_scanchunk<<<1, 64, 0, stream>>>(chunkoff, nchunks);
    k_scanwrite<<<nchunks, 256, 0, stream>>>(counts, N, chunkoff, offsets, cursor);
    k_fill<<<(E + 255) / 256, 256, 0, stream>>>(e_src, e_dst, E, cursor, csr_src);

    // ---- layer 1 aggregate ----
    agg1<<<(N + 3) / 4, 256, 0, stream>>>(xlr1, att1, b1, offsets, csr_src, h1b, N);

    // ---- layer 2 ----
    gemm_bf16<128, 64, ushort><<<dim3(2, (N + 127) / 128), 256, 0, stream>>>(h1b, wlr2t, xlr2, N, 128, 256);
    agg2<<<(N + 3) / 4, 256, 0, stream>>>(xlr2, att2, b2, offsets, csr_src, out, N);
}

// Round 6
// 340.546 us; speedup vs baseline: 2.1016x; 1.0517x over previous
//
#include <hip/hip_runtime.h>
#include <hip/hip_bf16.h>
#include <math.h>

#define NEG_SLOPE 0.2f

typedef __attribute__((ext_vector_type(8))) short short8;
typedef __attribute__((ext_vector_type(4))) float floatx4;
typedef __attribute__((ext_vector_type(2))) float floatx2;

__device__ inline ushort f2b(float f) {
    __hip_bfloat16 b = __float2bfloat16(f);
    return *(ushort*)&b;
}
// dword holding 2 bf16 (lo, hi) -> floatx2
__device__ inline floatx2 bf2x2(unsigned int d) {
    union { unsigned int i; float f; } lo, hi;
    lo.i = d << 16;
    hi.i = d & 0xffff0000u;
    floatx2 r = {lo.f, hi.f};
    return r;
}

// ---------------------------------------------------------------------------
// bf16 MFMA GEMM: C[M,N] = A[M,K] @ Bt[N,K]^T, all bf16 row-major.
// 256 threads = 4 waves. BN=128: waves 2x2 of 64x64 (acc[4][4]).
// BN=64: waves 4x1 of 32x64 (acc[2][4]) so small-N GEMMs get 2x the blocks.
// ---------------------------------------------------------------------------
template<int BM, int BN>
__global__ __launch_bounds__(256) void gemm_bf16(const ushort* __restrict__ A,
                                                 const ushort* __restrict__ Bt,
                                                 ushort* __restrict__ C,
                                                 int M, int N, int K)
{
    constexpr int SA = 40;                       // LDS row stride (pad 8 bf16)
    constexpr int WTM = (BN == 64) ? 32 : 64;    // wave tile M
    constexpr int WM  = BM / WTM;                // waves along M
    constexpr int IT  = WTM / 16;
    constexpr int JT  = 4;                       // wave tile N = 64
    __shared__ ushort As[BM * SA];
    __shared__ ushort Bs[BN * SA];
    const int tid = threadIdx.x;
    const int w = tid >> 6, lane = tid & 63;
    const int mw = (w % WM) * WTM;
    const int nw = (w / WM) * 64;
    const int m0 = blockIdx.y * BM;
    const int n0 = blockIdx.x * BN;
    const int lm = lane & 15;
    const int kg = lane >> 4;

    floatx4 acc[IT][JT];
#pragma unroll
    for (int i = 0; i < IT; ++i)
#pragma unroll
        for (int j = 0; j < JT; ++j) acc[i][j] = (floatx4)0.f;

    for (int k0 = 0; k0 < K; k0 += 32) {
#pragma unroll
        for (int it = 0; it < BM / 64; ++it) {
            int idx = it * 256 + tid;
            int row = idx >> 2, kc = idx & 3;
            int grow = m0 + row;
            if (grow >= M) grow = M - 1;
            short8 v = *(const short8*)&A[(size_t)grow * K + k0 + kc * 8];
            *(short8*)&As[row * SA + kc * 8] = v;
        }
#pragma unroll
        for (int it = 0; it < BN / 64; ++it) {
            int idx = it * 256 + tid;
            int row = idx >> 2, kc = idx & 3;
            short8 v = *(const short8*)&Bt[(size_t)(n0 + row) * K + k0 + kc * 8];
            *(short8*)&Bs[row * SA + kc * 8] = v;
        }
        __syncthreads();
        short8 a[IT], b[JT];
#pragma unroll
        for (int i = 0; i < IT; ++i)
            a[i] = *(const short8*)&As[(mw + i * 16 + lm) * SA + kg * 8];
#pragma unroll
        for (int j = 0; j < JT; ++j)
            b[j] = *(const short8*)&Bs[(nw + j * 16 + lm) * SA + kg * 8];
#pragma unroll
        for (int i = 0; i < IT; ++i)
#pragma unroll
            for (int j = 0; j < JT; ++j)
                acc[i][j] = __builtin_amdgcn_mfma_f32_16x16x32_bf16(a[i], b[j], acc[i][j], 0, 0, 0);
        __syncthreads();
    }

#pragma unroll
    for (int i = 0; i < IT; ++i) {
        int rbase = m0 + mw + i * 16 + (lane >> 4) * 4;
#pragma unroll
        for (int j = 0; j < JT; ++j) {
            int col = n0 + nw + j * 16 + lm;
#pragma unroll
            for (int r = 0; r < 4; ++r) {
                int row = rbase + r;
                if (row < M) C[(size_t)row * N + col] = f2b(acc[i][j][r]);
            }
        }
    }
}

// ---------------------------------------------------------------------------
// Fused prep: x fp32->bf16 cast, 4 weight transposes+casts, degree count.
// counts must be zeroed first (stream-ordered memset).
// Block ranges: [0,XB) xcast, [XB,XB+640) weights, rest count.
// ---------------------------------------------------------------------------
__global__ void k_prep(const float* __restrict__ x, ushort* __restrict__ xb, int XB,
                       const float* __restrict__ Wl1, const float* __restrict__ Wr1,
                       const float* __restrict__ Wl2, const float* __restrict__ Wr2,
                       ushort* __restrict__ wlr1t, ushort* __restrict__ wlr2t,
                       const int* __restrict__ dst, int E, int* __restrict__ counts)
{
    const int b = blockIdx.x;
    const int t = threadIdx.x;
    if (b < XB) {                                 // x cast: 8 floats/thread
        int i = b * 2048 + t * 8;
        float4 f0 = *(const float4*)&x[i];
        float4 f1 = *(const float4*)&x[i + 4];
        short8 o;
        o[0] = (short)f2b(f0.x); o[1] = (short)f2b(f0.y);
        o[2] = (short)f2b(f0.z); o[3] = (short)f2b(f0.w);
        o[4] = (short)f2b(f1.x); o[5] = (short)f2b(f1.y);
        o[6] = (short)f2b(f1.z); o[7] = (short)f2b(f1.w);
        *(short8*)&xb[i] = o;
    } else if (b < XB + 640) {                    // 163840 weight elements
        int i = (b - XB) * 256 + t;
        if (i < 65536) {
            int k = i >> 8, n = i & 255;
            wlr1t[n * 256 + k] = f2b(Wl1[i]);
        } else if (i < 131072) {
            int j = i - 65536;
            int k = j >> 8, n = j & 255;
            wlr1t[65536 + n * 256 + k] = f2b(Wr1[j]);
        } else if (i < 147456) {
            int j = i - 131072;
            int k = j >> 6, n = j & 63;
            wlr2t[n * 256 + k] = f2b(Wl2[j]);
        } else {
            int j = i - 147456;
            int k = j >> 6, n = j & 63;
            wlr2t[16384 + n * 256 + k] = f2b(Wr2[j]);
        }
    } else {
        int i = (b - XB - 640) * 256 + t;
        if (i < E) atomicAdd(&counts[dst[i]], 1);
    }
}

// ---------------------------------------------------------------------------
// CSR build (scan + fill). csr_off stores BYTE offsets into xlr1 (src*1024);
// agg2 derives its offset as >>2.
// ---------------------------------------------------------------------------
__global__ void k_chunksum(const int* __restrict__ counts, int N, int* __restrict__ chunk)
{
    __shared__ int sm[256];
    const int t = threadIdx.x;
    const int base = blockIdx.x * 1024;
    int s = 0;
    for (int i = t; i < 1024; i += 256) {
        int idx = base + i;
        s += (idx < N) ? counts[idx] : 0;
    }
    sm[t] = s;
    __syncthreads();
    for (int off = 128; off; off >>= 1) {
        if (t < off) sm[t] += sm[t + off];
        __syncthreads();
    }
    if (t == 0) chunk[blockIdx.x] = sm[0];
}

__global__ void k_scanchunk(int* __restrict__ chunk, int nchunks)
{
    // single wave: shuffle prefix scan over <=64 chunk sums
    const int t = threadIdx.x;
    int v = (t < nchunks) ? chunk[t] : 0;
    int inc = v;
#pragma unroll
    for (int off = 1; off < 64; off <<= 1) {
        int y = __shfl_up(inc, off);
        if (t >= off) inc += y;
    }
    if (t < nchunks) chunk[t] = inc - v;          // exclusive
    if (t == nchunks - 1) chunk[nchunks] = inc;   // total
}

__global__ void k_scanwrite(const int* __restrict__ counts, int N,
                            const int* __restrict__ chunk,
                            int* __restrict__ offsets, int* __restrict__ cursor)
{
    __shared__ int sm[256];
    const int t = threadIdx.x;
    const int base = blockIdx.x * 1024 + t * 4;
    int v[4];
    int s = 0;
#pragma unroll
    for (int i = 0; i < 4; ++i) {
        v[i] = (base + i < N) ? counts[base + i] : 0;
        s += v[i];
    }
    sm[t] = s;
    __syncthreads();
    for (int off = 1; off < 256; off <<= 1) {
        int y = (t >= off) ? sm[t - off] : 0;
        __syncthreads();
        sm[t] += y;
        __syncthreads();
    }
    int run = chunk[blockIdx.x] + sm[t] - s;
#pragma unroll
    for (int i = 0; i < 4; ++i) {
        if (base + i < N) {
            offsets[base + i] = run;
            cursor[base + i] = run;
        }
        run += v[i];
    }
    if (blockIdx.x == 0 && t == 0) offsets[N] = chunk[gridDim.x];
}

__global__ void k_fill(const int* __restrict__ src, const int* __restrict__ dst,
                       int E, int* __restrict__ cursor, int* __restrict__ csr_off)
{
    int i = blockIdx.x * blockDim.x + threadIdx.x;
    if (i < E) {
        int d = dst[i];
        int pos = atomicAdd(&cursor[d], 1);
        csr_off[pos] = src[i] * 1024;             // byte offset into xlr1 rows
    }
}

// ---------------------------------------------------------------------------
// Layer-1 aggregation: one wave per node, 2 edge-slots x 32 lanes, 8 ch/lane.
// Per-slot loop bounds (exact masking, no wasted tail loads), depth-2 gather
// prefetch + 1-ahead index prefetch, precomputed byte offsets, packed fp32.
// xlr: row 1024 B (xl at +0, xr at +512 B).
// ---------------------------------------------------------------------------
__global__ __launch_bounds__(256) void agg1(const ushort* __restrict__ xlr,
                                            const float* __restrict__ att,
                                            const float* __restrict__ bias,
                                            const int* __restrict__ offsets,
                                            const int* __restrict__ csr_off,
                                            ushort* __restrict__ h1, int N)
{
    const int wave = blockIdx.x * 4 + (threadIdx.x >> 6);
    const int lane = threadIdx.x & 63;
    if (wave >= N) return;
    const int n = wave;
    const int g = lane >> 5;                        // edge slot 0/1
    const int sl = lane & 31;
    const int elem = (sl >> 2) * 32 + (sl & 3) * 8; // head*32 + quad*8
    const char* __restrict__ xbase = (const char*)xlr;
    const int ebyte = elem * 2;

    floatx2 attv2[4], xrv2[4];
    {
        uint4 xr8 = *(const uint4*)(xbase + (size_t)n * 1024 + 512 + ebyte);
        unsigned int xw[4] = {xr8.x, xr8.y, xr8.z, xr8.w};
#pragma unroll
        for (int i = 0; i < 4; ++i) {
            attv2[i] = *(const floatx2*)&att[elem + 2 * i];
            xrv2[i] = bf2x2(xw[i]);
        }
    }
    float m = -1e30f, l = 0.f;
    floatx2 acc2[4] = {(floatx2)0.f, (floatx2)0.f, (floatx2)0.f, (floatx2)0.f};

    const int beg = offsets[n], end = offsets[n + 1];
    uint4 vA, vB;
    int oC;
    {
        int k0 = beg + g;
        if (k0 < end) vA = *(const uint4*)(xbase + (unsigned)csr_off[k0] + ebyte);
        if (k0 + 2 < end) vB = *(const uint4*)(xbase + (unsigned)csr_off[k0 + 2] + ebyte);
        if (k0 + 4 < end) oC = csr_off[k0 + 4];
    }
    for (int kk = beg + g; kk < end; kk += 2) {
        uint4 cur = vA;
        vA = vB;
        if (kk + 4 < end) vB = *(const uint4*)(xbase + (unsigned)oC + ebyte);
        if (kk + 6 < end) oC = csr_off[kk + 6];

        unsigned int cw[4] = {cur.x, cur.y, cur.z, cur.w};
        floatx2 xl2[4];
        floatx2 u2 = (floatx2)0.f;
#pragma unroll
        for (int i = 0; i < 4; ++i) {
            xl2[i] = bf2x2(cw[i]);
            floatx2 t = xl2[i] + xrv2[i];
            t = __builtin_elementwise_max(t, t * NEG_SLOPE);   // leaky relu
            u2 += t * attv2[i];
        }
        float u = u2.x + u2.y;
        u += __shfl_xor(u, 1);                      // 4-lane channel-group reduce
        u += __shfl_xor(u, 2);
        // single-exp branchless online softmax update
        float e = __expf(-fabsf(u - m));
        bool kp = (m >= u);
        float sc = kp ? 1.f : e;
        float p  = kp ? e : 1.f;
        m = fmaxf(m, u);
#pragma unroll
        for (int i = 0; i < 4; ++i) acc2[i] = acc2[i] * sc + xl2[i] * p;
        l = fmaf(l, sc, p);
    }
    // merge the two slot states (butterfly over lane^32)
    {
        float mo = __shfl_xor(m, 32);
        float lo = __shfl_xor(l, 32);
        float nm = fmaxf(m, mo);
        float ea = __expf(m - nm);
        float eb = __expf(mo - nm);
#pragma unroll
        for (int i = 0; i < 4; ++i) {
            floatx2 ao = {__shfl_xor(acc2[i].x, 32), __shfl_xor(acc2[i].y, 32)};
            acc2[i] = acc2[i] * ea + ao * eb;
        }
        l = l * ea + lo * eb;
    }
    if (g == 0) {
        float rl = 1.f / (l + 1e-16f);
        short8 o;
#pragma unroll
        for (int i = 0; i < 4; ++i) {
            float v0 = fmaf(acc2[i].x, rl, bias[elem + 2 * i]);
            float v1 = fmaf(acc2[i].y, rl, bias[elem + 2 * i + 1]);
            o[2 * i]     = (short)f2b(fmaxf(v0, 0.f));
            o[2 * i + 1] = (short)f2b(fmaxf(v1, 0.f));
        }
        *(short8*)&h1[(size_t)n * 256 + elem] = o;
    }
}

// ---------------------------------------------------------------------------
// Layer-2 aggregation: one wave per node, 4 edge-slots x 16 lanes, 4 ch/lane.
// Same pipeline structure as agg1; row byte offset = csr_off >> 2.
// xlr2: row 256 B (xl at +0, xr at +128 B). Fused bias + log_softmax.
// ---------------------------------------------------------------------------
__global__ __launch_bounds__(256) void agg2(const ushort* __restrict__ xlr,
                                            const float* __restrict__ att,
                                            const float* __restrict__ bias,
                                            const int* __restrict__ offsets,
                                            const int* __restrict__ csr_off,
                                            float* __restrict__ out, int N)
{
    const int wave = blockIdx.x * 4 + (threadIdx.x >> 6);
    const int lane = threadIdx.x & 63;
    if (wave >= N) return;
    const int n = wave;
    const int g = lane >> 4;
    const int c0 = (lane & 15) * 4;
    const char* __restrict__ xbase = (const char*)xlr;
    const int cbyte = c0 * 2;

    floatx2 attv2[2], xrv2[2];
    {
        uint2 xr4 = *(const uint2*)(xbase + (size_t)n * 256 + 128 + cbyte);
        attv2[0] = *(const floatx2*)&att[c0];
        attv2[1] = *(const floatx2*)&att[c0 + 2];
        xrv2[0] = bf2x2(xr4.x);
        xrv2[1] = bf2x2(xr4.y);
    }
    float m = -1e30f, l = 0.f;
    floatx2 acc2[2] = {(floatx2)0.f, (floatx2)0.f};

    const int beg = offsets[n], end = offsets[n + 1];
    uint2 vA, vB;
    int oC;
    {
        int k0 = beg + g;
        if (k0 < end) vA = *(const uint2*)(xbase + ((unsigned)csr_off[k0] >> 2) + cbyte);
        if (k0 + 4 < end) vB = *(const uint2*)(xbase + ((unsigned)csr_off[k0 + 4] >> 2) + cbyte);
        if (k0 + 8 < end) oC = csr_off[k0 + 8];
    }
    for (int kk = beg + g; kk < end; kk += 4) {
        uint2 cur = vA;
        vA = vB;
        if (kk + 8 < end) vB = *(const uint2*)(xbase + ((unsigned)oC >> 2) + cbyte);
        if (kk + 12 < end) oC = csr_off[kk + 12];

        floatx2 xl2[2];
        xl2[0] = bf2x2(cur.x);
        xl2[1] = bf2x2(cur.y);
        floatx2 u2 = (floatx2)0.f;
#pragma unroll
        for (int i = 0; i < 2; ++i) {
            floatx2 t = xl2[i] + xrv2[i];
            t = __builtin_elementwise_max(t, t * NEG_SLOPE);
            u2 += t * attv2[i];
        }
        float u = u2.x + u2.y;
        u += __shfl_xor(u, 1);
        u += __shfl_xor(u, 2);
        u += __shfl_xor(u, 4);
        u += __shfl_xor(u, 8);
        float e = __expf(-fabsf(u - m));
        bool kp = (m >= u);
        float sc = kp ? 1.f : e;
        float p  = kp ? e : 1.f;
        m = fmaxf(m, u);
#pragma unroll
        for (int i = 0; i < 2; ++i) acc2[i] = acc2[i] * sc + xl2[i] * p;
        l = fmaf(l, sc, p);
    }
    // merge the 4 slot states
#pragma unroll
    for (int off = 16; off <= 32; off <<= 1) {
        float mo = __shfl_xor(m, off);
        float lo = __shfl_xor(l, off);
        float nm = fmaxf(m, mo);
        float sa = __expf(m - nm);
        float sb = __expf(mo - nm);
#pragma unroll
        for (int i = 0; i < 2; ++i) {
            floatx2 ao = {__shfl_xor(acc2[i].x, off), __shfl_xor(acc2[i].y, off)};
            acc2[i] = acc2[i] * sa + ao * sb;
        }
        l = l * sa + lo * sb;
        m = nm;
    }
    float rl = 1.f / (l + 1e-16f);
    float h[4];
    h[0] = acc2[0].x * rl + bias[c0];
    h[1] = acc2[0].y * rl + bias[c0 + 1];
    h[2] = acc2[1].x * rl + bias[c0 + 2];
    h[3] = acc2[1].y * rl + bias[c0 + 3];

    float mx = fmaxf(fmaxf(h[0], h[1]), fmaxf(h[2], h[3]));
    mx = fmaxf(mx, __shfl_xor(mx, 1));
    mx = fmaxf(mx, __shfl_xor(mx, 2));
    mx = fmaxf(mx, __shfl_xor(mx, 4));
    mx = fmaxf(mx, __shfl_xor(mx, 8));
    float ssum = __expf(h[0] - mx) + __expf(h[1] - mx) + __expf(h[2] - mx) + __expf(h[3] - mx);
    ssum += __shfl_xor(ssum, 1);
    ssum += __shfl_xor(ssum, 2);
    ssum += __shfl_xor(ssum, 4);
    ssum += __shfl_xor(ssum, 8);
    float lg = __logf(ssum);
    if (g == 0) {
        float4 o1 = make_float4(h[0], h[1], h[2], h[3]);
        *(float4*)&out[(size_t)n * 64 + c0] = o1;
        float4 o2 = make_float4(h[0] - mx - lg, h[1] - mx - lg, h[2] - mx - lg, h[3] - mx - lg);
        *(float4*)&out[(size_t)(N + n) * 64 + c0] = o2;
    }
}

// ---------------------------------------------------------------------------
extern "C" void kernel_launch(void* const* d_in, const int* in_sizes, int n_in,
                              void* d_out, int out_size, void* d_ws, size_t ws_size,
                              hipStream_t stream)
{
    const float* x    = (const float*)d_in[0];
    const int*   ei   = (const int*)d_in[1];
    const float* Wl1  = (const float*)d_in[2];
    const float* Wr1  = (const float*)d_in[3];
    const float* att1 = (const float*)d_in[4];
    const float* b1   = (const float*)d_in[5];
    const float* Wl2  = (const float*)d_in[6];
    const float* Wr2  = (const float*)d_in[7];
    const float* att2 = (const float*)d_in[8];
    const float* b2   = (const float*)d_in[9];
    float* out = (float*)d_out;

    const int F = 256;
    const int E = in_sizes[1] / 2;
    const int N = in_sizes[0] / F;

    const int* e_src = ei;
    const int* e_dst = ei + E;

    // ---- workspace layout ----
    ushort* xb    = (ushort*)d_ws;                   // [N][256] bf16 x
    ushort* wlr1t = xb + (size_t)N * 256;            // [512][256]  (Wl1|Wr1)^T
    ushort* wlr2t = wlr1t + 512 * 256;               // [128][256]  (Wl2|Wr2)^T
    ushort* xlr1  = wlr2t + 128 * 256;               // [N][512]  xl|xr
    ushort* h1b   = xlr1 + (size_t)N * 512;          // [N][256]
    ushort* xlr2  = h1b + (size_t)N * 256;           // [N][128]  xl|xr
    int* offsets  = (int*)(xlr2 + (size_t)N * 128);  // N+1
    int* cursor   = offsets + (N + 1);               // N+1
    int* counts   = cursor + (N + 1);                // N
    int* chunkoff = counts + N;                      // <=64+1
    int* csr_off  = chunkoff + 66;                   // E (byte offsets)

    const int nchunks = (N + 1023) / 1024;
    const int XB = (N * 256) / 2048;                 // x-cast blocks (8 elem/thread)

    // ---- fused prep (x cast + weights cast/transpose + degree count) ----
    hipMemsetAsync(counts, 0, (size_t)N * sizeof(int), stream);
    k_prep<<<XB + 640 + (E + 255) / 256, 256, 0, stream>>>(
        x, xb, XB, Wl1, Wr1, Wl2, Wr2, wlr1t, wlr2t, e_dst, E, counts);

    // ---- layer-1 GEMM (independent of CSR scan chain) ----
    gemm_bf16<128, 128><<<dim3(4, (N + 127) / 128), 256, 0, stream>>>(xb, wlr1t, xlr1, N, 512, F);

    // ---- CSR scan + fill ----
    k_chunksum<<<nchunks, 256, 0, stream>>>(counts, N, chunkoff);
    k_scanchunk<<<1, 64, 0, stream>>>(chunkoff, nchunks);
    k_scanwrite<<<nchunks, 256, 0, stream>>>(counts, N, chunkoff, offsets, cursor);
    k_fill<<<(E + 255) / 256, 256, 0, stream>>>(e_src, e_dst, E, cursor, csr_off);

    // ---- layer 1 aggregate ----
    agg1<<<(N + 3) / 4, 256, 0, stream>>>(xlr1, att1, b1, offsets, csr_off, h1b, N);

    // ---- layer 2 ----
    gemm_bf16<128, 64><<<dim3(2, (N + 127) / 128), 256, 0, stream>>>(h1b, wlr2t, xlr2, N, 128, 256);
    agg2<<<(N + 3) / 4, 256, 0, stream>>>(xlr2, att2, b2, offsets, csr_off, out, N);
}